// Round 8
// baseline (987.163 us; speedup 1.0000x reference)
//
#include <hip/hip_runtime.h>
#include <cmath>

// ---------------------------------------------------------------------------
// Hetero-SAGE GNN (4 layers, 10 relations, D=128) + edge classifier.
// R17: deeper intra-kernel overlap + lean-first block order.
//   R16 post-mortem: fused1=64us vs agg-alone 52us — lean Yq blocks placed
//   AFTER agg ran in the drain tail at low concurrency. Fix: lean blocks
//   FIRST (burst at full concurrency under the first agg blocks).
//   New back-half: F2 = mgemm{visit-transform only} (782 blk); F3 = fused3 =
//   lean no-LDS m1 (K=256, A=[mean|x_old], in-place w/ pre-store barrier,
//   bitwise-identical k-order to mgemm) placed first || agg_visit blocks —
//   m1's ~15us hides under agg_visit's gather stalls.
//   Layer: F1{leanYq||agg_small} -> F2{visit} -> F3{leanM1||agg_visit}.
// R16: fused1 (agg_small || lean Yq). R11: factored classifier. R10: merged
//   weighted visit-CSR. R9: bucket-sort CSR build. R8: split-f16 H/L planes,
//   f16x3 MFMA GEMMs, h-only Y/gathers, layer-3 pruning.
// ---------------------------------------------------------------------------

typedef _Float16 f16x8 __attribute__((ext_vector_type(8)));
typedef float f32x4 __attribute__((ext_vector_type(4)));

#define NREL 10
#define NCOUNTS 546000
#define NEDGES  2300000
#define NVISIT  100000
#define NVEDGES 1150000
#define PLW 546816
#define WT_ELEMS (4 * PLW + 69632)
#define XELEMS 18688000UL   // 146000*128
#define SELEMS 5888000UL    // 46000*128
#define NBKT 873
#define BCAP 5056

struct GatherMeta { const float* emb[6]; const int* nid[6]; int rows[6]; int off[6]; };
struct BkMeta {
  const int* ei[NREL]; int E[NREL]; int cbc[NREL]; int ndst[NREL];
  int sh[NREL]; int bb[NREL]; int nb[NREL];
};
struct MTask {
  const _Float16* AH0; const _Float16* AL0;  // k in [0,128)
  const _Float16* AH1; const _Float16* AL1;  // k in [128,256)
  const _Float16* W;                         // [2][128][Kpad] h then l plane
  const float* bias;                         // nullable
  _Float16* outH; _Float16* outL;            // outL nullable (h-only output)
  int M, blkOff, K, relu;
};
struct MMeta { MTask t[6]; int nTasks; };
// F1: lean Y_q gemm blocks first, then agg_small blocks
struct F1Meta {
  const int* rp[5]; _Float16* mH[5]; _Float16* mL[5]; int aM[5]; int aOff[5]; int nAgg;
  const _Float16* gAH[5]; const _Float16* gAL[5]; const _Float16* gW[5];
  _Float16* gY[5]; int gM[5]; int gOff[5]; int nG; int leanTotal;
};
// F3: lean m1 gemm blocks first (K=256, in-place), then agg_visit blocks
struct F3Meta {
  const _Float16* mMH[5]; const _Float16* mML[5];   // A k<128 (means)
  _Float16* mXH[5]; _Float16* mXL[5];               // A k>=128 AND output (in-place)
  const _Float16* mW[5]; const float* mB[5];
  int mM[5]; int mOff[5]; int nM1; int m1Total;
};

// ---------------- conv0: emb -> split H/L planes ---------------------------
__global__ __launch_bounds__(256) void conv0(GatherMeta g, _Float16* __restrict__ H,
                                             _Float16* __restrict__ L) {
  int t = blockIdx.y;
  int i = blockIdx.x * 256 + threadIdx.x;
  if (i >= g.rows[t] * 16) return;
  int row = i >> 4, q = i & 15;
  int s = g.nid[t][row];
  const float* p = g.emb[t] + (size_t)s * 128 + q * 8;
  float4 v0 = *(const float4*)p;
  float4 v1 = *(const float4*)(p + 4);
  float v[8] = {v0.x, v0.y, v0.z, v0.w, v1.x, v1.y, v1.z, v1.w};
  f16x8 h, l;
  #pragma unroll
  for (int j = 0; j < 8; ++j) {
    h[j] = (_Float16)v[j];
    l[j] = (_Float16)(v[j] - (float)h[j]);
  }
  size_t o = (size_t)(g.off[t] + row) * 128 + q * 8;
  *(f16x8*)(H + o) = h;
  *(f16x8*)(L + o) = l;
}

// ---------------- CSR build: block-aggregated bucket sort ------------------
__global__ __launch_bounds__(256) void bkt_p1(BkMeta bm, int* __restrict__ bcur,
                                              int* __restrict__ bdata) {
  __shared__ int cnt[128];
  __shared__ int base[128];
  __shared__ unsigned short rnk[4096];
  int r = blockIdx.y;
  int E = bm.E[r], sh = bm.sh[r], bb = bm.bb[r], nb = bm.nb[r];
  int tid = threadIdx.x;
  if (tid < 128) cnt[tid] = 0;
  __syncthreads();
  int e0 = blockIdx.x * 4096;
  if (e0 >= E) return;
  const int* dstp = bm.ei[r] + E;
  const int* srcp = bm.ei[r];
  #pragma unroll
  for (int i = 0; i < 16; ++i) {
    int e = e0 + i * 256 + tid;
    if (e < E) {
      int b = dstp[e] >> sh;
      rnk[i * 256 + tid] = (unsigned short)atomicAdd(&cnt[b], 1);
    }
  }
  __syncthreads();
  if (tid < nb && cnt[tid] > 0) base[tid] = atomicAdd(&bcur[bb + tid], cnt[tid]);
  __syncthreads();
  #pragma unroll
  for (int i = 0; i < 16; ++i) {
    int e = e0 + i * 256 + tid;
    if (e < E) {
      int d = dstp[e];
      int b = d >> sh;
      int pos = base[b] + (int)rnk[i * 256 + tid];
      if (pos < BCAP)
        bdata[(size_t)(bb + b) * BCAP + pos] = ((d & ((1 << sh) - 1)) << 17) | srcp[e];
    }
  }
}

// p2a: per-bucket LDS hist -> coalesced counts
__global__ __launch_bounds__(256) void bkt_p2a(BkMeta bm, const int* __restrict__ bcur,
                                               const int* __restrict__ bdata,
                                               int* __restrict__ counts) {
  __shared__ int hist[2048];
  int g = blockIdx.x;
  int r = 0;
  #pragma unroll
  for (int i = 1; i < NREL; ++i) if (g >= bm.bb[i]) r = i;
  int lb = g - bm.bb[r];
  int sh = bm.sh[r], dpb = 1 << sh;
  int tid = threadIdx.x;
  for (int d = tid; d < dpb; d += 256) hist[d] = 0;
  __syncthreads();
  int cnt = bcur[g]; if (cnt > BCAP) cnt = BCAP;
  const int* bd = bdata + (size_t)g * BCAP;
  for (int i = tid; i < cnt; i += 256) atomicAdd(&hist[((unsigned)bd[i]) >> 17], 1);
  __syncthreads();
  int dBase = lb << sh;
  int dMax = bm.ndst[r] - dBase; if (dMax > dpb) dMax = dpb;
  for (int d = tid; d < dMax; d += 256) counts[bm.cbc[r] + dBase + d] = hist[d];
}

// ---------------- global scan (3-phase) ------------------------------------
__global__ __launch_bounds__(1024) void scan1(const int* __restrict__ counts,
                                              int* __restrict__ partials) {
  __shared__ int s[1024];
  int i = blockIdx.x * 1024 + threadIdx.x;
  s[threadIdx.x] = (i < NCOUNTS) ? counts[i] : 0;
  __syncthreads();
  for (int off = 512; off > 0; off >>= 1) {
    if (threadIdx.x < off) s[threadIdx.x] += s[threadIdx.x + off];
    __syncthreads();
  }
  if (threadIdx.x == 0) partials[blockIdx.x] = s[0];
}

__global__ __launch_bounds__(1024) void scan2(int* __restrict__ partials, int nb) {
  __shared__ int s[1024];
  int t = threadIdx.x;
  int v = (t < nb) ? partials[t] : 0;
  s[t] = v;
  __syncthreads();
  for (int off = 1; off < 1024; off <<= 1) {
    int add = (t >= off) ? s[t - off] : 0;
    __syncthreads();
    s[t] += add;
    __syncthreads();
  }
  if (t < nb) partials[t] = s[t] - v;  // exclusive
}

__global__ __launch_bounds__(1024) void scan3(const int* __restrict__ counts,
                                              int* __restrict__ prefix,
                                              const int* __restrict__ partials) {
  __shared__ int s[1024];
  int t = threadIdx.x;
  int i = blockIdx.x * 1024 + t;
  int v = (i < NCOUNTS) ? counts[i] : 0;
  s[t] = v;
  __syncthreads();
  for (int off = 1; off < 1024; off <<= 1) {
    int add = (t >= off) ? s[t - off] : 0;
    __syncthreads();
    s[t] += add;
    __syncthreads();
  }
  int P = partials[blockIdx.x] + s[t] - v;
  if (i < NCOUNTS) prefix[i] = P;
  if (blockIdx.x == 0 && t == 0) prefix[NCOUNTS] = NEDGES;
}

// p2b: per-bucket LDS counting sort -> contiguous coalesced esrc run
__global__ __launch_bounds__(256) void bkt_p2b(BkMeta bm, const int* __restrict__ bcur,
                                               const int* __restrict__ bdata,
                                               const int* __restrict__ prefix,
                                               int* __restrict__ esrc) {
  __shared__ int pk[BCAP];
  __shared__ int srt[BCAP];
  __shared__ int cur[2048];
  __shared__ int part[256];
  __shared__ int baseSh;
  int g = blockIdx.x;
  int r = 0;
  #pragma unroll
  for (int i = 1; i < NREL; ++i) if (g >= bm.bb[i]) r = i;
  int lb = g - bm.bb[r];
  int sh = bm.sh[r], dpb = 1 << sh;
  int tid = threadIdx.x;
  int cnt = bcur[g]; if (cnt > BCAP) cnt = BCAP;
  const int* bd = bdata + (size_t)g * BCAP;
  for (int d = tid; d < dpb; d += 256) cur[d] = 0;
  for (int i = tid; i < cnt; i += 256) pk[i] = bd[i];
  __syncthreads();
  for (int i = tid; i < cnt; i += 256) atomicAdd(&cur[((unsigned)pk[i]) >> 17], 1);
  __syncthreads();
  int seg = (dpb + 255) >> 8;
  int s = 0;
  int b0 = tid * seg;
  for (int j = 0; j < seg; ++j) {
    int idx = b0 + j;
    if (idx < dpb) { int v = cur[idx]; cur[idx] = s; s += v; }
  }
  part[tid] = s;
  __syncthreads();
  for (int off = 1; off < 256; off <<= 1) {
    int add = (tid >= off) ? part[tid - off] : 0;
    __syncthreads();
    part[tid] += add;
    __syncthreads();
  }
  int myoff = part[tid] - s;
  for (int j = 0; j < seg; ++j) {
    int idx = b0 + j;
    if (idx < dpb) cur[idx] += myoff;
  }
  if (tid == 0) baseSh = prefix[bm.cbc[r] + (lb << sh)];
  __syncthreads();
  for (int i = tid; i < cnt; i += 256) {
    int p = pk[i];
    int pos = atomicAdd(&cur[((unsigned)p) >> 17], 1);
    srt[pos] = p & 0x1FFFF;
  }
  __syncthreads();
  int base = baseSh;
  for (int i = tid; i < cnt; i += 256) esrc[base + i] = srt[i];
}

// ---------------- merged weighted visit CSR (built once) -------------------
__global__ __launch_bounds__(256) void merge_visit(const int* __restrict__ prefix,
                                                   const int* __restrict__ esrc,
                                                   int* __restrict__ mprefix,
                                                   int2* __restrict__ mesrc) {
  const int cbc[5]  = {0, 124000, 232000, 342000, 446000};
  const int yoff[5] = {0, 20000, 24000, 32000, 42000};
  int v = blockIdx.x * 256 + threadIdx.x;
  if (v >= NVISIT) return;
  int e0[5], e1[5];
  int base = 0;
  #pragma unroll
  for (int q = 0; q < 5; ++q) {
    e0[q] = prefix[cbc[q] + v];
    e1[q] = prefix[cbc[q] + v + 1];
    base += e0[q] - prefix[cbc[q]];
  }
  mprefix[v] = base;
  if (v == NVISIT - 1) {
    int t = base;
    #pragma unroll
    for (int q = 0; q < 5; ++q) t += e1[q] - e0[q];
    mprefix[NVISIT] = t;
  }
  int pos = base;
  #pragma unroll
  for (int q = 0; q < 5; ++q) {
    int d = e1[q] - e0[q];
    if (d > 0) {
      int wb = __float_as_int(1.f / (float)d);
      for (int e = e0[q]; e < e1[q]; ++e)
        mesrc[pos++] = make_int2(yoff[q] + esrc[e], wb);
    }
  }
}

// ---------------- weight split/transpose prep ------------------------------
__global__ __launch_bounds__(256) void prep_split(
    const float* __restrict__ W_l, const float* __restrict__ b_l,
    const float* __restrict__ W_r, const float* __restrict__ cw1,
    _Float16* __restrict__ Wt, float* __restrict__ visitSumB) {
  const int visitRel[5] = {0, 3, 5, 7, 9};
  const int inRel[5] = {1, 2, 4, 6, 8};
  int gid = blockIdx.x * 256 + threadIdx.x;
  if (gid < 1048576) {
    int l = gid >> 18, o = gid & 262143;
    float val; size_t base; int n, k, Kpad;
    if (o < 163840) {          // small stacks, K=256
      int t = o >> 15, e = o & 32767;
      k = e >> 7; n = e & 127; Kpad = 264;
      int r = inRel[t];
      val = (k < 128) ? W_l[(size_t)(l * 10 + r) * 16384 + k * 128 + n]
                      : W_r[(size_t)(l * 10 + r) * 16384 + (k - 128) * 128 + n];
      base = (size_t)l * PLW + t * 67584;
    } else if (o < 245760) {   // trans Wl, K=128
      int q = (o - 163840) >> 14, e = (o - 163840) & 16383;
      k = e >> 7; n = e & 127; Kpad = 136;
      val = W_l[(size_t)(l * 10 + visitRel[q]) * 16384 + k * 128 + n];
      base = (size_t)l * PLW + 337920 + q * 34816;
    } else {                   // SumWr, K=128
      int e = o - 245760;
      k = e >> 7; n = e & 127; Kpad = 136;
      val = 0.f;
      #pragma unroll
      for (int q = 0; q < 5; ++q)
        val += W_r[(size_t)(l * 10 + visitRel[q]) * 16384 + k * 128 + n];
      base = (size_t)l * PLW + 512000;
    }
    _Float16 h = (_Float16)val;
    _Float16 lo = (_Float16)(val - (float)h);
    Wt[base + (size_t)n * Kpad + k] = h;
    Wt[base + (size_t)(128 + n) * Kpad + k] = lo;
  } else if (gid < 1081344) {  // cls W1 -> two K=128 split layouts (top|bot)
    int e = gid - 1048576;
    int k = e >> 7, n = e & 127;
    float val = cw1[(size_t)k * 128 + n];
    _Float16 h = (_Float16)val;
    _Float16 lo = (_Float16)(val - (float)h);
    size_t base = (size_t)4 * PLW + (k < 128 ? 0 : 34816);
    int kk = k & 127;
    Wt[base + (size_t)n * 136 + kk] = h;
    Wt[base + (size_t)(128 + n) * 136 + kk] = lo;
  } else if (gid < 1081856) {  // visit summed bias
    int e = gid - 1081344;
    int l = e >> 7, c = e & 127;
    float val = 0.f;
    #pragma unroll
    for (int q = 0; q < 5; ++q) val += b_l[(l * 10 + visitRel[q]) * 128 + c];
    visitSumB[e] = val;
  }
}

// ---------------- F1: lean Y_q GEMM (first) || agg_small (R12 body) --------
__global__ __launch_bounds__(256, 8) void fused1(F1Meta f,
                                                 const _Float16* __restrict__ xvH,
                                                 const int* __restrict__ esrc) {
  int b = blockIdx.x;
  int tid = threadIdx.x;
  if (b < f.leanTotal) {
    // ---- lean Y_q gemm: Y = x_small @ Wl_q, h-only out ----
    int g = 0;
    #pragma unroll
    for (int i = 1; i < 5; ++i) if (i < f.nG && b >= f.gOff[i]) g = i;
    int blockRow = (b - f.gOff[g]) * 32;
    int lane = tid & 63, wave = tid >> 6;
    int quad = lane >> 4, lm = lane & 15;
    int wr = wave >> 1, wc = wave & 1;
    const _Float16* AH = f.gAH[g];
    const _Float16* AL = f.gAL[g];
    const _Float16* W = f.gW[g];
    int M = f.gM[g];
    int ar = blockRow + wr * 16 + lm;
    if (ar >= M) ar = M - 1;  // clamp (dup row ok)
    f32x4 acc[4];
    #pragma unroll
    for (int nt = 0; nt < 4; ++nt) acc[nt] = (f32x4){0.f, 0.f, 0.f, 0.f};
    for (int ks = 0; ks < 128; ks += 32) {
      f16x8 ah = *(const f16x8*)(AH + (size_t)ar * 128 + ks + quad * 8);
      f16x8 al = *(const f16x8*)(AL + (size_t)ar * 128 + ks + quad * 8);
      #pragma unroll
      for (int nt = 0; nt < 4; ++nt) {
        int n = wc * 64 + nt * 16 + lm;
        f16x8 bh = *(const f16x8*)(W + (size_t)n * 136 + ks + quad * 8);
        f16x8 bl = *(const f16x8*)(W + (size_t)(128 + n) * 136 + ks + quad * 8);
        acc[nt] = __builtin_amdgcn_mfma_f32_16x16x32_f16(ah, bh, acc[nt], 0, 0, 0);
        acc[nt] = __builtin_amdgcn_mfma_f32_16x16x32_f16(ah, bl, acc[nt], 0, 0, 0);
        acc[nt] = __builtin_amdgcn_mfma_f32_16x16x32_f16(al, bh, acc[nt], 0, 0, 0);
      }
    }
    _Float16* Y = f.gY[g];
    #pragma unroll
    for (int i = 0; i < 4; ++i) {
      int grow = blockRow + wr * 16 + quad * 4 + i;
      if (grow >= M) continue;
      #pragma unroll
      for (int nt = 0; nt < 4; ++nt)
        Y[(size_t)grow * 128 + wc * 64 + nt * 16 + lm] = (_Float16)acc[nt][i];
    }
    return;
  }
  // ---- agg_small ----
  b -= f.leanTotal;
  int t = 0;
  #pragma unroll
  for (int i = 1; i < 5; ++i) if (i < f.nAgg && b >= f.aOff[i]) t = i;
  int row = (b - f.aOff[t]) * 16 + (tid >> 4);
  if (row >= f.aM[t]) return;
  int q = tid & 15;
  const int* rp = f.rp[t];
  int e0 = rp[row], e1 = rp[row + 1];
  float a[8];
  #pragma unroll
  for (int j = 0; j < 8; ++j) a[j] = 0.f;
  int e = e0;
  for (; e + 4 <= e1; e += 4) {
    int s0 = esrc[e], s1 = esrc[e + 1], s2 = esrc[e + 2], s3 = esrc[e + 3];
    f16x8 v0 = *(const f16x8*)(xvH + (size_t)s0 * 128 + q * 8);
    f16x8 v1 = *(const f16x8*)(xvH + (size_t)s1 * 128 + q * 8);
    f16x8 v2 = *(const f16x8*)(xvH + (size_t)s2 * 128 + q * 8);
    f16x8 v3 = *(const f16x8*)(xvH + (size_t)s3 * 128 + q * 8);
    #pragma unroll
    for (int j = 0; j < 8; ++j)
      a[j] += ((float)v0[j] + (float)v1[j]) + ((float)v2[j] + (float)v3[j]);
  }
  for (; e < e1; ++e) {
    int s = esrc[e];
    f16x8 v = *(const f16x8*)(xvH + (size_t)s * 128 + q * 8);
    #pragma unroll
    for (int j = 0; j < 8; ++j) a[j] += (float)v[j];
  }
  float inv = (e1 > e0) ? 1.f / (float)(e1 - e0) : 0.f;
  f16x8 h, l;
  #pragma unroll
  for (int j = 0; j < 8; ++j) {
    float v = a[j] * inv;
    h[j] = (_Float16)v;
    l[j] = (_Float16)(v - (float)h[j]);
  }
  size_t o = (size_t)row * 128 + q * 8;
  *(f16x8*)(f.mH[t] + o) = h;
  *(f16x8*)(f.mL[t] + o) = l;
}

// ---------------- F3: lean m1 GEMM (first, K=256, in-place) || agg_visit ---
// lean m1: x_small = relu([mean | x_old] @ [Wl;Wr] + b), split out, in-place.
// Same k-order / MFMA triple / accumulation as mgemm => bitwise-identical.
// __syncthreads() before stores: all waves' A-reads (incl. x_old) complete
// before any in-place write.
__global__ __launch_bounds__(256, 8) void fused3(F3Meta f,
                                                 const int* __restrict__ mprefix,
                                                 const int2* __restrict__ mesrc,
                                                 const _Float16* __restrict__ YH,
                                                 _Float16* __restrict__ xvH,
                                                 _Float16* __restrict__ xvL,
                                                 int doRelu) {
  int b = blockIdx.x;
  int tid = threadIdx.x;
  if (b < f.m1Total) {
    int g = 0;
    #pragma unroll
    for (int i = 1; i < 5; ++i) if (i < f.nM1 && b >= f.mOff[i]) g = i;
    int blockRow = (b - f.mOff[g]) * 32;
    int lane = tid & 63, wave = tid >> 6;
    int quad = lane >> 4, lm = lane & 15;
    int wr = wave >> 1, wc = wave & 1;
    int M = f.mM[g];
    int ar = blockRow + wr * 16 + lm;
    if (ar >= M) ar = M - 1;  // clamp stays within this block's rows
    const _Float16* MH = f.mMH[g];
    const _Float16* ML = f.mML[g];
    _Float16* XH = f.mXH[g];
    _Float16* XL = f.mXL[g];
    const _Float16* W = f.mW[g];
    f32x4 acc[4];
    #pragma unroll
    for (int nt = 0; nt < 4; ++nt) acc[nt] = (f32x4){0.f, 0.f, 0.f, 0.f};
    for (int ks = 0; ks < 256; ks += 32) {
      const _Float16* AH = (ks < 128) ? MH : (const _Float16*)XH;
      const _Float16* AL = (ks < 128) ? ML : (const _Float16*)XL;
      int kk = ks & 127;
      f16x8 ah = *(const f16x8*)(AH + (size_t)ar * 128 + kk + quad * 8);
      f16x8 al = *(const f16x8*)(AL + (size_t)ar * 128 + kk + quad * 8);
      #pragma unroll
      for (int nt = 0; nt < 4; ++nt) {
        int n = wc * 64 + nt * 16 + lm;
        f16x8 bh = *(const f16x8*)(W + (size_t)n * 264 + ks + quad * 8);
        f16x8 bl = *(const f16x8*)(W + (size_t)(128 + n) * 264 + ks + quad * 8);
        acc[nt] = __builtin_amdgcn_mfma_f32_16x16x32_f16(ah, bh, acc[nt], 0, 0, 0);
        acc[nt] = __builtin_amdgcn_mfma_f32_16x16x32_f16(ah, bl, acc[nt], 0, 0, 0);
        acc[nt] = __builtin_amdgcn_mfma_f32_16x16x32_f16(al, bh, acc[nt], 0, 0, 0);
      }
    }
    __syncthreads();  // all A-reads done before in-place writes
    float bv[4];
    #pragma unroll
    for (int nt = 0; nt < 4; ++nt) bv[nt] = f.mB[g][wc * 64 + nt * 16 + lm];
    #pragma unroll
    for (int i = 0; i < 4; ++i) {
      int grow = blockRow + wr * 16 + quad * 4 + i;
      if (grow >= M) continue;
      size_t ob = (size_t)grow * 128 + wc * 64 + lm;
      #pragma unroll
      for (int nt = 0; nt < 4; ++nt) {
        float v = acc[nt][i] + bv[nt];
        if (doRelu) v = fmaxf(v, 0.f);
        _Float16 h = (_Float16)v;
        XH[ob + nt * 16] = h;
        XL[ob + nt * 16] = (_Float16)(v - (float)h);
      }
    }
    return;
  }
  // ---- agg_visit (R12 body) ----
  b -= f.m1Total;
  int row = b * 16 + (tid >> 4);
  if (row >= NVISIT) return;
  int q = tid & 15;
  size_t o = (size_t)row * 128 + q * 8;
  f16x8 h0 = *(f16x8*)(xvH + o);
  f16x8 l0 = *(f16x8*)(xvL + o);
  float a[8];
  #pragma unroll
  for (int j = 0; j < 8; ++j) a[j] = (float)h0[j] + (float)l0[j];
  int e0 = mprefix[row], e1 = mprefix[row + 1];
  int e = e0;
  for (; e + 4 <= e1; e += 4) {
    int2 p0 = mesrc[e], p1 = mesrc[e + 1], p2 = mesrc[e + 2], p3 = mesrc[e + 3];
    f16x8 v0 = *(const f16x8*)(YH + (size_t)p0.x * 128 + q * 8);
    f16x8 v1 = *(const f16x8*)(YH + (size_t)p1.x * 128 + q * 8);
    f16x8 v2 = *(const f16x8*)(YH + (size_t)p2.x * 128 + q * 8);
    f16x8 v3 = *(const f16x8*)(YH + (size_t)p3.x * 128 + q * 8);
    float w0 = __int_as_float(p0.y), w1 = __int_as_float(p1.y);
    float w2 = __int_as_float(p2.y), w3 = __int_as_float(p3.y);
    #pragma unroll
    for (int j = 0; j < 8; ++j)
      a[j] += (w0 * (float)v0[j] + w1 * (float)v1[j]) +
              (w2 * (float)v2[j] + w3 * (float)v3[j]);
  }
  for (; e < e1; ++e) {
    int2 p = mesrc[e];
    f16x8 v = *(const f16x8*)(YH + (size_t)p.x * 128 + q * 8);
    float w = __int_as_float(p.y);
    #pragma unroll
    for (int j = 0; j < 8; ++j) a[j] += w * (float)v[j];
  }
  f16x8 h, l;
  #pragma unroll
  for (int j = 0; j < 8; ++j) {
    float v = doRelu ? fmaxf(a[j], 0.f) : a[j];
    h[j] = (_Float16)v;
    l[j] = (_Float16)(v - (float)h[j]);
  }
  *(f16x8*)(xvH + o) = h;
  *(f16x8*)(xvL + o) = l;
}

// ---------------- MFMA f16x3 GEMM, multi-task, split-plane A ---------------
__global__ __launch_bounds__(256, 2) void mgemm(MMeta mm) {
  int b = blockIdx.x;
  int ti = 0;
  for (int i = 1; i < mm.nTasks; ++i) if (b >= mm.t[i].blkOff) ti = i;
  MTask tk = mm.t[ti];
  int blockRow = (b - tk.blkOff) * 128;
  int Kpad = tk.K + 8;

  __shared__ _Float16 Ash[2][128][72];
  int tid = threadIdx.x;
  int wave = tid >> 6, lane = tid & 63;
  int quad = lane >> 4, lm = lane & 15;
  int wr = wave >> 1, wc = wave & 1;

  f32x4 acc[4][4];
  #pragma unroll
  for (int i = 0; i < 4; ++i)
    #pragma unroll
    for (int j = 0; j < 4; ++j) acc[i][j] = (f32x4){0.f, 0.f, 0.f, 0.f};

  const _Float16* wrowH[4];
  const _Float16* wrowL[4];
  #pragma unroll
  for (int nt = 0; nt < 4; ++nt) {
    int n = wc * 64 + nt * 16 + lm;
    wrowH[nt] = tk.W + (size_t)n * Kpad;
    wrowL[nt] = tk.W + (size_t)(128 + n) * Kpad;
  }

  int sr = tid >> 1, sk = (tid & 1) * 32;
  int gr = blockRow + sr; if (gr >= tk.M) gr = tk.M - 1;  // clamp (dup row ok)
  for (int k0 = 0; k0 < tk.K; k0 += 64) {
    const _Float16* AH = (k0 < 128) ? tk.AH0 : tk.AH1;
    const _Float16* AL = (k0 < 128) ? tk.AL0 : tk.AL1;
    size_t abase = (size_t)gr * 128 + (k0 & 127) + sk;
    #pragma unroll
    for (int c = 0; c < 4; ++c) {
      *(f16x8*)&Ash[0][sr][sk + c * 8] = *(const f16x8*)(AH + abase + c * 8);
      *(f16x8*)&Ash[1][sr][sk + c * 8] = *(const f16x8*)(AL + abase + c * 8);
    }
    __syncthreads();
    #pragma unroll
    for (int ks = 0; ks < 64; ks += 32) {
      int kf = k0 + ks + quad * 8;
      f16x8 bh[4], bl[4];
      #pragma unroll
      for (int nt = 0; nt < 4; ++nt) {
        bh[nt] = *(const f16x8*)(wrowH[nt] + kf);
        bl[nt] = *(const f16x8*)(wrowL[nt] + kf);
      }
      #pragma unroll
      for (int mt = 0; mt < 4; ++mt) {
        int r = wr * 64 + mt * 16 + lm;
        f16x8 ah = *(const f16x8*)&Ash[0][r][ks + quad * 8];
        f16x8 al = *(const f16x8*)&Ash[1][r][ks + quad * 8];
        #pragma unroll
        for (int nt = 0; nt < 4; ++nt) {
          acc[mt][nt] = __builtin_amdgcn_mfma_f32_16x16x32_f16(ah, bh[nt], acc[mt][nt], 0, 0, 0);
          acc[mt][nt] = __builtin_amdgcn_mfma_f32_16x16x32_f16(ah, bl[nt], acc[mt][nt], 0, 0, 0);
          acc[mt][nt] = __builtin_amdgcn_mfma_f32_16x16x32_f16(al, bh[nt], acc[mt][nt], 0, 0, 0);
        }
      }
    }
    __syncthreads();
  }

  float bv[4];
  #pragma unroll
  for (int nt = 0; nt < 4; ++nt)
    bv[nt] = tk.bias ? tk.bias[wc * 64 + nt * 16 + lm] : 0.f;
  #pragma unroll
  for (int mt = 0; mt < 4; ++mt) {
    #pragma unroll
    for (int i = 0; i < 4; ++i) {
      int grow = blockRow + wr * 64 + mt * 16 + quad * 4 + i;
      if (grow >= tk.M) continue;
      size_t ob = (size_t)grow * 128 + wc * 64 + lm;
      #pragma unroll
      for (int nt = 0; nt < 4; ++nt) {
        float v = acc[mt][nt][i] + bv[nt];
        if (tk.relu) v = fmaxf(v, 0.f);
        _Float16 h = (_Float16)v;
        tk.outH[ob + nt * 16] = h;
        if (tk.outL) tk.outL[ob + nt * 16] = (_Float16)(v - (float)h);
      }
    }
  }
}

// ---------------- factored classifier edge pass ----------------------------
__global__ __launch_bounds__(256) void cls_edge(
    const _Float16* __restrict__ UH, const _Float16* __restrict__ UL,
    const _Float16* __restrict__ VH, const _Float16* __restrict__ VL,
    const int* __restrict__ eli, const float* __restrict__ w2,
    const float* __restrict__ b2, const float* __restrict__ y,
    float* __restrict__ lossOut, float* __restrict__ pred, int M) {
  __shared__ float lsum[4];
  int tid = threadIdx.x;
  int q = tid & 15;
  int lane = tid & 63;
  float w2v[8];
  #pragma unroll
  for (int j = 0; j < 8; ++j) w2v[j] = w2[q * 8 + j];
  float bias = b2[0];
  float lacc = 0.f;
  int e0 = blockIdx.x * 128 + (tid >> 4);
  #pragma unroll
  for (int p = 0; p < 8; ++p) {
    int e = e0 + p * 16;
    if (e < M) {
      int vi = eli[e], di = eli[M + e];
      size_t uo = (size_t)vi * 128 + q * 8;
      size_t vo = (size_t)di * 128 + q * 8;
      f16x8 uh = *(const f16x8*)(UH + uo);
      f16x8 ul = *(const f16x8*)(UL + uo);
      f16x8 vh = *(const f16x8*)(VH + vo);
      f16x8 vl = *(const f16x8*)(VL + vo);
      float part = 0.f;
      #pragma unroll
      for (int j = 0; j < 8; ++j) {
        float t = ((float)uh[j] + (float)ul[j]) + ((float)vh[j] + (float)vl[j]);
        part += fmaxf(t, 0.f) * w2v[j];
      }
      part += __shfl_xor(part, 1);
      part += __shfl_xor(part, 2);
      part += __shfl_xor(part, 4);
      part += __shfl_xor(part, 8);
      if (q == 0) {
        float z = part + bias;
        pred[e] = z;
        lacc += fmaxf(z, 0.f) + log1pf(expf(-fabsf(z))) - z * y[e];
      }
    }
  }
  lacc += __shfl_xor(lacc, 16);
  lacc += __shfl_xor(lacc, 32);
  if (lane == 0) lsum[tid >> 6] = lacc;
  __syncthreads();
  if (tid == 0)
    atomicAdd(lossOut, (lsum[0] + lsum[1] + lsum[2] + lsum[3]) * (1.0f / 200000.0f));
}

// ---------------------------------------------------------------------------
extern "C" void kernel_launch(void* const* d_in, const int* in_sizes, int n_in,
                              void* d_out, int out_size, void* d_ws, size_t ws_size,
                              hipStream_t stream) {
  static const int kRows[6] = {20000, 100000, 4000, 8000, 10000, 4000};
  static const int kOff[6]  = {0, 20000, 120000, 124000, 132000, 142000};
  static const int kSmallT[5]   = {0, 2, 3, 4, 5};
  static const int kInRel[5]    = {1, 2, 4, 6, 8};
  static const int kCbcIn[5]    = {100000, 120000, 224000, 332000, 442000};
  static const int kYOff[5]     = {0, 20000, 24000, 32000, 42000};
  static const int kAggOff[5]   = {0, 1250, 1500, 2000, 2625};   // 16-row blocks
  static const int kLeanOff[5]  = {0, 625, 750, 1000, 1313};     // 32-row blocks
  const int kAggTotal = 2875, kLeanTotal = 1438;
  // bucket config (rel order: pv,vp,vs,sv,vpr,prv,vd,dv,vdr,drv)
  static const int kCbcA[NREL]  = {0, 100000, 120000, 124000, 224000,
                                   232000, 332000, 342000, 442000, 446000};
  static const int kEhA[NREL]   = {100000, 100000, 300000, 300000, 200000,
                                   200000, 250000, 250000, 300000, 300000};
  static const int kNdst[NREL]  = {100000, 20000, 4000, 100000, 8000,
                                   100000, 10000, 100000, 4000, 100000};
  static const int kSh[NREL]    = {11, 9, 5, 10, 7, 10, 7, 10, 5, 10};
  static const int kNB[NREL]    = {49, 40, 125, 98, 63, 98, 79, 98, 125, 98};
  static const int kBB[NREL]    = {0, 49, 89, 214, 312, 375, 473, 552, 650, 775};

  const float* W_l = (const float*)d_in[22];
  const float* b_l = (const float*)d_in[23];
  const float* W_r = (const float*)d_in[24];
  const float* cw1 = (const float*)d_in[25];
  const float* cb1 = (const float*)d_in[26];
  const float* cw2 = (const float*)d_in[27];
  const float* cb2 = (const float*)d_in[28];
  const int* eli = (const int*)d_in[29];
  const float* ylab = (const float*)d_in[30];

  // workspace layout
  _Float16* H = (_Float16*)d_ws;                 // XELEMS
  _Float16* L = H + XELEMS;                      // XELEMS
  _Float16* meanH = L + XELEMS;                  // SELEMS
  _Float16* meanL = meanH + SELEMS;              // SELEMS
  _Float16* YH = meanL + SELEMS;                 // SELEMS
  _Float16* Wt = YH + SELEMS;                    // WT_ELEMS
  int* prefix = (int*)(Wt + WT_ELEMS);           // 546,004
  int* counts = prefix + 546004;                 // 546,000 (reused as mprefix)
  int* esrc = counts + NCOUNTS;                  // 2,300,000
  int* partials = esrc + NEDGES;                 // 1,024
  float* visitSumB = (float*)(partials + 1024);  // 512
  int* bcur = (int*)(visitSumB + 512);           // NBKT (+pad)
  int* bdata = bcur + 1024;                      // NBKT * BCAP ints (reused as mesrc)

  int* mprefix = counts;        // free after scan3
  int2* mesrc = (int2*)bdata;   // free after bkt_p2b

  // classifier U/V tables (alive only after layer-3; reuse dead regions)
  _Float16* UH = meanH;
  _Float16* VH = meanH + (size_t)NVISIT * 128;
  _Float16* VL = VH + (size_t)4000 * 128;
  _Float16* UL = (_Float16*)prefix;

  BkMeta bm;
  for (int r = 0; r < NREL; ++r) {
    bm.ei[r] = (const int*)d_in[12 + r];
    bm.E[r] = kEhA[r];
    bm.cbc[r] = kCbcA[r];
    bm.ndst[r] = kNdst[r];
    bm.sh[r] = kSh[r];
    bm.bb[r] = kBB[r];
    bm.nb[r] = kNB[r];
  }

  hipMemsetAsync(bcur, 0, NBKT * sizeof(int), stream);
  hipMemsetAsync(d_out, 0, sizeof(float), stream);

  prep_split<<<(1081856 + 255) / 256, 256, 0, stream>>>(W_l, b_l, W_r, cw1, Wt, visitSumB);

  GatherMeta gm;
  for (int t = 0; t < 6; ++t) {
    gm.nid[t] = (const int*)d_in[2 * t];
    gm.emb[t] = (const float*)d_in[2 * t + 1];
    gm.rows[t] = kRows[t];
    gm.off[t] = kOff[t];
  }
  conv0<<<dim3(6250, 6), 256, 0, stream>>>(gm, H, L);

  // CSR build
  bkt_p1<<<dim3(74, NREL), 256, 0, stream>>>(bm, bcur, bdata);
  bkt_p2a<<<dim3(NBKT), 256, 0, stream>>>(bm, bcur, bdata, counts);
  scan1<<<534, 1024, 0, stream>>>(counts, partials);
  scan2<<<1, 1024, 0, stream>>>(partials, 534);
  scan3<<<534, 1024, 0, stream>>>(counts, prefix, partials);
  bkt_p2b<<<dim3(NBKT), 256, 0, stream>>>(bm, bcur, bdata, prefix, esrc);
  merge_visit<<<dim3((NVISIT + 255) / 256), 256, 0, stream>>>(prefix, esrc, mprefix, mesrc);

  _Float16* xvH = H + (size_t)kOff[1] * 128;
  _Float16* xvL = L + (size_t)kOff[1] * 128;

  for (int l = 0; l < 4; ++l) {
    int doRelu = (l < 3);
    int last = (l == 3);
    _Float16* LW = Wt + (size_t)l * PLW;

    // F1: lean Y_q (first) || agg_small
    F1Meta f1;
    f1.leanTotal = kLeanTotal;
    for (int q = 0; q < 5; ++q) {
      size_t so = (size_t)kOff[kSmallT[q]] * 128;
      f1.gAH[q] = H + so;
      f1.gAL[q] = L + so;
      f1.gW[q] = LW + 337920 + (size_t)q * 34816;
      f1.gY[q] = YH + (size_t)kYOff[q] * 128;
      f1.gM[q] = kRows[kSmallT[q]];
      f1.gOff[q] = kLeanOff[q];
    }
    f1.nG = 5;
    int aggTotal;
    if (!last) {
      for (int t = 0; t < 5; ++t) {
        f1.rp[t] = prefix + kCbcIn[t];
        f1.mH[t] = meanH + (size_t)kYOff[t] * 128;
        f1.mL[t] = meanL + (size_t)kYOff[t] * 128;
        f1.aM[t] = kRows[kSmallT[t]];
        f1.aOff[t] = kAggOff[t];
      }
      f1.nAgg = 5;
      aggTotal = kAggTotal;
    } else {
      f1.rp[0] = prefix + kCbcIn[4];
      f1.mH[0] = meanH + (size_t)kYOff[4] * 128;
      f1.mL[0] = meanL + (size_t)kYOff[4] * 128;
      f1.aM[0] = 4000;
      f1.aOff[0] = 0;
      for (int t = 1; t < 5; ++t) { f1.rp[t] = nullptr; f1.mH[t] = nullptr; f1.mL[t] = nullptr; f1.aM[t] = 0; f1.aOff[t] = 0; }
      f1.nAgg = 1;
      aggTotal = 250;
    }
    fused1<<<dim3(kLeanTotal + aggTotal), 256, 0, stream>>>(f1, xvH, esrc);

    // F2: visit transform only: x_v = x_v @ SumWr + Sumb (in-place, split)
    MMeta m;
    m.nTasks = 1;
    m.t[0].AH0 = xvH; m.t[0].AL0 = xvL;
    m.t[0].AH1 = nullptr; m.t[0].AL1 = nullptr;
    m.t[0].W = LW + 512000;
    m.t[0].bias = visitSumB + l * 128;
    m.t[0].outH = xvH; m.t[0].outL = xvL;   // in-place (block-local rows)
    m.t[0].M = NVISIT;
    m.t[0].blkOff = 0;
    m.t[0].K = 128;
    m.t[0].relu = 0;
    mgemm<<<dim3(782), 256, 0, stream>>>(m);

    // F3: lean m1 (first, in-place) || agg_visit
    F3Meta f3;
    if (!last) {
      for (int t = 0; t < 5; ++t) {
        size_t mo = (size_t)kYOff[t] * 128;
        size_t so = (size_t)kOff[kSmallT[t]] * 128;
        f3.mMH[t] = meanH + mo; f3.mML[t] = meanL + mo;
        f3.mXH[t] = H + so;     f3.mXL[t] = L + so;
        f3.mW[t] = LW + (size_t)t * 67584;
        f3.mB[t] = b_l + (size_t)(l * 10 + kInRel[t]) * 128;
        f3.mM[t] = kRows[kSmallT[t]];
        f3.mOff[t] = kLeanOff[t];
      }
      f3.nM1 = 5;
      f3.m1Total = kLeanTotal;
    } else {
      size_t mo = (size_t)kYOff[4] * 128;
      size_t so = (size_t)kOff[5] * 128;   // drug
      f3.mMH[0] = meanH + mo; f3.mML[0] = meanL + mo;
      f3.mXH[0] = H + so;     f3.mXL[0] = L + so;
      f3.mW[0] = LW + (size_t)4 * 67584;
      f3.mB[0] = b_l + (size_t)(l * 10 + kInRel[4]) * 128;
      f3.mM[0] = 4000;
      f3.mOff[0] = 0;
      for (int t = 1; t < 5; ++t) { f3.mMH[t] = nullptr; f3.mML[t] = nullptr; f3.mXH[t] = nullptr; f3.mXL[t] = nullptr; f3.mW[t] = nullptr; f3.mB[t] = nullptr; f3.mM[t] = 0; f3.mOff[t] = 0; }
      f3.nM1 = 1;
      f3.m1Total = 125;
    }
    fused3<<<dim3(f3.m1Total + 6250), 256, 0, stream>>>(f3, mprefix, mesrc, YH, xvH, xvL, doRelu);
  }

  // classifier precompute: U = xv@W1top + b1 (split), V = xd@W1bot (split)
  MMeta muv;
  muv.nTasks = 2;
  muv.t[0].AH0 = xvH; muv.t[0].AL0 = xvL;
  muv.t[0].AH1 = nullptr; muv.t[0].AL1 = nullptr;
  muv.t[0].W = Wt + (size_t)4 * PLW;
  muv.t[0].bias = cb1;
  muv.t[0].outH = UH; muv.t[0].outL = UL;
  muv.t[0].M = NVISIT;
  muv.t[0].blkOff = 0;
  muv.t[0].K = 128;
  muv.t[0].relu = 0;
  muv.t[1].AH0 = H + (size_t)kOff[5] * 128; muv.t[1].AL0 = L + (size_t)kOff[5] * 128;
  muv.t[1].AH1 = nullptr; muv.t[1].AL1 = nullptr;
  muv.t[1].W = Wt + (size_t)4 * PLW + 34816;
  muv.t[1].bias = nullptr;
  muv.t[1].outH = VH; muv.t[1].outL = VL;
  muv.t[1].M = 4000;
  muv.t[1].blkOff = 782;
  muv.t[1].K = 128;
  muv.t[1].relu = 0;
  mgemm<<<dim3(782 + 32), 256, 0, stream>>>(muv);

  const int ML = 200000;
  cls_edge<<<dim3((ML + 127) / 128), 256, 0, stream>>>(
      UH, UL, VH, VL, eli, cw2, cb2, ylab,
      (float*)d_out, (float*)d_out + 1, ML);
}

// Round 9
// 921.821 us; speedup vs baseline: 1.0709x; 1.0709x over previous
//
#include <hip/hip_runtime.h>
#include <cmath>

// ---------------------------------------------------------------------------
// Hetero-SAGE GNN (4 layers, 10 relations, D=128) + edge classifier.
// R18: single-variable fix. R17's back-half split REGRESSED (fused3=80us:
//   lean K=256 m1 at 32 VGPR serialized 8 dependent B-reads/k-step and
//   re-read the 135KB W tile per 32-row block; it also broke the efficient
//   m1||visit co-schedule inside mgemm). Revert to the R16 schedule
//   (F1=fused1, F2=mgemm{m1 x5, visit}, F3=agg_visit; 911us proven) keeping
//   ONLY R17's lean-first block order inside fused1 (R16 post-mortem: agg
//   blocks filled all resident slots before any lean MFMA block dispatched).
// R16: fused1 (agg_small || lean Yq). R11: factored classifier. R10: merged
//   weighted visit-CSR. R9: bucket-sort CSR build. R8: split-f16 H/L planes,
//   f16x3 MFMA GEMMs, h-only Y/gathers, layer-3 pruning.
// ---------------------------------------------------------------------------

typedef _Float16 f16x8 __attribute__((ext_vector_type(8)));
typedef float f32x4 __attribute__((ext_vector_type(4)));

#define NREL 10
#define NCOUNTS 546000
#define NEDGES  2300000
#define NVISIT  100000
#define NVEDGES 1150000
#define PLW 546816
#define WT_ELEMS (4 * PLW + 69632)
#define XELEMS 18688000UL   // 146000*128
#define SELEMS 5888000UL    // 46000*128
#define NBKT 873
#define BCAP 5056

struct GatherMeta { const float* emb[6]; const int* nid[6]; int rows[6]; int off[6]; };
struct BkMeta {
  const int* ei[NREL]; int E[NREL]; int cbc[NREL]; int ndst[NREL];
  int sh[NREL]; int bb[NREL]; int nb[NREL];
};
struct MTask {
  const _Float16* AH0; const _Float16* AL0;  // k in [0,128)
  const _Float16* AH1; const _Float16* AL1;  // k in [128,256)
  const _Float16* W;                         // [2][128][Kpad] h then l plane
  const float* bias;                         // nullable
  _Float16* outH; _Float16* outL;            // outL nullable (h-only output)
  int M, blkOff, K, relu;
};
struct MMeta { MTask t[6]; int nTasks; };
// F1: lean Y_q gemm blocks first, then agg_small blocks
struct F1Meta {
  const int* rp[5]; _Float16* mH[5]; _Float16* mL[5]; int aM[5]; int aOff[5]; int nAgg;
  const _Float16* gAH[5]; const _Float16* gAL[5]; const _Float16* gW[5];
  _Float16* gY[5]; int gM[5]; int gOff[5]; int nG; int leanTotal;
};

// ---------------- conv0: emb -> split H/L planes ---------------------------
__global__ __launch_bounds__(256) void conv0(GatherMeta g, _Float16* __restrict__ H,
                                             _Float16* __restrict__ L) {
  int t = blockIdx.y;
  int i = blockIdx.x * 256 + threadIdx.x;
  if (i >= g.rows[t] * 16) return;
  int row = i >> 4, q = i & 15;
  int s = g.nid[t][row];
  const float* p = g.emb[t] + (size_t)s * 128 + q * 8;
  float4 v0 = *(const float4*)p;
  float4 v1 = *(const float4*)(p + 4);
  float v[8] = {v0.x, v0.y, v0.z, v0.w, v1.x, v1.y, v1.z, v1.w};
  f16x8 h, l;
  #pragma unroll
  for (int j = 0; j < 8; ++j) {
    h[j] = (_Float16)v[j];
    l[j] = (_Float16)(v[j] - (float)h[j]);
  }
  size_t o = (size_t)(g.off[t] + row) * 128 + q * 8;
  *(f16x8*)(H + o) = h;
  *(f16x8*)(L + o) = l;
}

// ---------------- CSR build: block-aggregated bucket sort ------------------
__global__ __launch_bounds__(256) void bkt_p1(BkMeta bm, int* __restrict__ bcur,
                                              int* __restrict__ bdata) {
  __shared__ int cnt[128];
  __shared__ int base[128];
  __shared__ unsigned short rnk[4096];
  int r = blockIdx.y;
  int E = bm.E[r], sh = bm.sh[r], bb = bm.bb[r], nb = bm.nb[r];
  int tid = threadIdx.x;
  if (tid < 128) cnt[tid] = 0;
  __syncthreads();
  int e0 = blockIdx.x * 4096;
  if (e0 >= E) return;
  const int* dstp = bm.ei[r] + E;
  const int* srcp = bm.ei[r];
  #pragma unroll
  for (int i = 0; i < 16; ++i) {
    int e = e0 + i * 256 + tid;
    if (e < E) {
      int b = dstp[e] >> sh;
      rnk[i * 256 + tid] = (unsigned short)atomicAdd(&cnt[b], 1);
    }
  }
  __syncthreads();
  if (tid < nb && cnt[tid] > 0) base[tid] = atomicAdd(&bcur[bb + tid], cnt[tid]);
  __syncthreads();
  #pragma unroll
  for (int i = 0; i < 16; ++i) {
    int e = e0 + i * 256 + tid;
    if (e < E) {
      int d = dstp[e];
      int b = d >> sh;
      int pos = base[b] + (int)rnk[i * 256 + tid];
      if (pos < BCAP)
        bdata[(size_t)(bb + b) * BCAP + pos] = ((d & ((1 << sh) - 1)) << 17) | srcp[e];
    }
  }
}

// p2a: per-bucket LDS hist -> coalesced counts
__global__ __launch_bounds__(256) void bkt_p2a(BkMeta bm, const int* __restrict__ bcur,
                                               const int* __restrict__ bdata,
                                               int* __restrict__ counts) {
  __shared__ int hist[2048];
  int g = blockIdx.x;
  int r = 0;
  #pragma unroll
  for (int i = 1; i < NREL; ++i) if (g >= bm.bb[i]) r = i;
  int lb = g - bm.bb[r];
  int sh = bm.sh[r], dpb = 1 << sh;
  int tid = threadIdx.x;
  for (int d = tid; d < dpb; d += 256) hist[d] = 0;
  __syncthreads();
  int cnt = bcur[g]; if (cnt > BCAP) cnt = BCAP;
  const int* bd = bdata + (size_t)g * BCAP;
  for (int i = tid; i < cnt; i += 256) atomicAdd(&hist[((unsigned)bd[i]) >> 17], 1);
  __syncthreads();
  int dBase = lb << sh;
  int dMax = bm.ndst[r] - dBase; if (dMax > dpb) dMax = dpb;
  for (int d = tid; d < dMax; d += 256) counts[bm.cbc[r] + dBase + d] = hist[d];
}

// ---------------- global scan (3-phase) ------------------------------------
__global__ __launch_bounds__(1024) void scan1(const int* __restrict__ counts,
                                              int* __restrict__ partials) {
  __shared__ int s[1024];
  int i = blockIdx.x * 1024 + threadIdx.x;
  s[threadIdx.x] = (i < NCOUNTS) ? counts[i] : 0;
  __syncthreads();
  for (int off = 512; off > 0; off >>= 1) {
    if (threadIdx.x < off) s[threadIdx.x] += s[threadIdx.x + off];
    __syncthreads();
  }
  if (threadIdx.x == 0) partials[blockIdx.x] = s[0];
}

__global__ __launch_bounds__(1024) void scan2(int* __restrict__ partials, int nb) {
  __shared__ int s[1024];
  int t = threadIdx.x;
  int v = (t < nb) ? partials[t] : 0;
  s[t] = v;
  __syncthreads();
  for (int off = 1; off < 1024; off <<= 1) {
    int add = (t >= off) ? s[t - off] : 0;
    __syncthreads();
    s[t] += add;
    __syncthreads();
  }
  if (t < nb) partials[t] = s[t] - v;  // exclusive
}

__global__ __launch_bounds__(1024) void scan3(const int* __restrict__ counts,
                                              int* __restrict__ prefix,
                                              const int* __restrict__ partials) {
  __shared__ int s[1024];
  int t = threadIdx.x;
  int i = blockIdx.x * 1024 + t;
  int v = (i < NCOUNTS) ? counts[i] : 0;
  s[t] = v;
  __syncthreads();
  for (int off = 1; off < 1024; off <<= 1) {
    int add = (t >= off) ? s[t - off] : 0;
    __syncthreads();
    s[t] += add;
    __syncthreads();
  }
  int P = partials[blockIdx.x] + s[t] - v;
  if (i < NCOUNTS) prefix[i] = P;
  if (blockIdx.x == 0 && t == 0) prefix[NCOUNTS] = NEDGES;
}

// p2b: per-bucket LDS counting sort -> contiguous coalesced esrc run
__global__ __launch_bounds__(256) void bkt_p2b(BkMeta bm, const int* __restrict__ bcur,
                                               const int* __restrict__ bdata,
                                               const int* __restrict__ prefix,
                                               int* __restrict__ esrc) {
  __shared__ int pk[BCAP];
  __shared__ int srt[BCAP];
  __shared__ int cur[2048];
  __shared__ int part[256];
  __shared__ int baseSh;
  int g = blockIdx.x;
  int r = 0;
  #pragma unroll
  for (int i = 1; i < NREL; ++i) if (g >= bm.bb[i]) r = i;
  int lb = g - bm.bb[r];
  int sh = bm.sh[r], dpb = 1 << sh;
  int tid = threadIdx.x;
  int cnt = bcur[g]; if (cnt > BCAP) cnt = BCAP;
  const int* bd = bdata + (size_t)g * BCAP;
  for (int d = tid; d < dpb; d += 256) cur[d] = 0;
  for (int i = tid; i < cnt; i += 256) pk[i] = bd[i];
  __syncthreads();
  for (int i = tid; i < cnt; i += 256) atomicAdd(&cur[((unsigned)pk[i]) >> 17], 1);
  __syncthreads();
  int seg = (dpb + 255) >> 8;
  int s = 0;
  int b0 = tid * seg;
  for (int j = 0; j < seg; ++j) {
    int idx = b0 + j;
    if (idx < dpb) { int v = cur[idx]; cur[idx] = s; s += v; }
  }
  part[tid] = s;
  __syncthreads();
  for (int off = 1; off < 256; off <<= 1) {
    int add = (tid >= off) ? part[tid - off] : 0;
    __syncthreads();
    part[tid] += add;
    __syncthreads();
  }
  int myoff = part[tid] - s;
  for (int j = 0; j < seg; ++j) {
    int idx = b0 + j;
    if (idx < dpb) cur[idx] += myoff;
  }
  if (tid == 0) baseSh = prefix[bm.cbc[r] + (lb << sh)];
  __syncthreads();
  for (int i = tid; i < cnt; i += 256) {
    int p = pk[i];
    int pos = atomicAdd(&cur[((unsigned)p) >> 17], 1);
    srt[pos] = p & 0x1FFFF;
  }
  __syncthreads();
  int base = baseSh;
  for (int i = tid; i < cnt; i += 256) esrc[base + i] = srt[i];
}

// ---------------- merged weighted visit CSR (built once) -------------------
__global__ __launch_bounds__(256) void merge_visit(const int* __restrict__ prefix,
                                                   const int* __restrict__ esrc,
                                                   int* __restrict__ mprefix,
                                                   int2* __restrict__ mesrc) {
  const int cbc[5]  = {0, 124000, 232000, 342000, 446000};
  const int yoff[5] = {0, 20000, 24000, 32000, 42000};
  int v = blockIdx.x * 256 + threadIdx.x;
  if (v >= NVISIT) return;
  int e0[5], e1[5];
  int base = 0;
  #pragma unroll
  for (int q = 0; q < 5; ++q) {
    e0[q] = prefix[cbc[q] + v];
    e1[q] = prefix[cbc[q] + v + 1];
    base += e0[q] - prefix[cbc[q]];
  }
  mprefix[v] = base;
  if (v == NVISIT - 1) {
    int t = base;
    #pragma unroll
    for (int q = 0; q < 5; ++q) t += e1[q] - e0[q];
    mprefix[NVISIT] = t;
  }
  int pos = base;
  #pragma unroll
  for (int q = 0; q < 5; ++q) {
    int d = e1[q] - e0[q];
    if (d > 0) {
      int wb = __float_as_int(1.f / (float)d);
      for (int e = e0[q]; e < e1[q]; ++e)
        mesrc[pos++] = make_int2(yoff[q] + esrc[e], wb);
    }
  }
}

// ---------------- weight split/transpose prep ------------------------------
__global__ __launch_bounds__(256) void prep_split(
    const float* __restrict__ W_l, const float* __restrict__ b_l,
    const float* __restrict__ W_r, const float* __restrict__ cw1,
    _Float16* __restrict__ Wt, float* __restrict__ visitSumB) {
  const int visitRel[5] = {0, 3, 5, 7, 9};
  const int inRel[5] = {1, 2, 4, 6, 8};
  int gid = blockIdx.x * 256 + threadIdx.x;
  if (gid < 1048576) {
    int l = gid >> 18, o = gid & 262143;
    float val; size_t base; int n, k, Kpad;
    if (o < 163840) {          // small stacks, K=256
      int t = o >> 15, e = o & 32767;
      k = e >> 7; n = e & 127; Kpad = 264;
      int r = inRel[t];
      val = (k < 128) ? W_l[(size_t)(l * 10 + r) * 16384 + k * 128 + n]
                      : W_r[(size_t)(l * 10 + r) * 16384 + (k - 128) * 128 + n];
      base = (size_t)l * PLW + t * 67584;
    } else if (o < 245760) {   // trans Wl, K=128
      int q = (o - 163840) >> 14, e = (o - 163840) & 16383;
      k = e >> 7; n = e & 127; Kpad = 136;
      val = W_l[(size_t)(l * 10 + visitRel[q]) * 16384 + k * 128 + n];
      base = (size_t)l * PLW + 337920 + q * 34816;
    } else {                   // SumWr, K=128
      int e = o - 245760;
      k = e >> 7; n = e & 127; Kpad = 136;
      val = 0.f;
      #pragma unroll
      for (int q = 0; q < 5; ++q)
        val += W_r[(size_t)(l * 10 + visitRel[q]) * 16384 + k * 128 + n];
      base = (size_t)l * PLW + 512000;
    }
    _Float16 h = (_Float16)val;
    _Float16 lo = (_Float16)(val - (float)h);
    Wt[base + (size_t)n * Kpad + k] = h;
    Wt[base + (size_t)(128 + n) * Kpad + k] = lo;
  } else if (gid < 1081344) {  // cls W1 -> two K=128 split layouts (top|bot)
    int e = gid - 1048576;
    int k = e >> 7, n = e & 127;
    float val = cw1[(size_t)k * 128 + n];
    _Float16 h = (_Float16)val;
    _Float16 lo = (_Float16)(val - (float)h);
    size_t base = (size_t)4 * PLW + (k < 128 ? 0 : 34816);
    int kk = k & 127;
    Wt[base + (size_t)n * 136 + kk] = h;
    Wt[base + (size_t)(128 + n) * 136 + kk] = lo;
  } else if (gid < 1081856) {  // visit summed bias
    int e = gid - 1081344;
    int l = e >> 7, c = e & 127;
    float val = 0.f;
    #pragma unroll
    for (int q = 0; q < 5; ++q) val += b_l[(l * 10 + visitRel[q]) * 128 + c];
    visitSumB[e] = val;
  }
}

// ---------------- F1: lean Y_q GEMM (first) || agg_small (R12 body) --------
__global__ __launch_bounds__(256, 8) void fused1(F1Meta f,
                                                 const _Float16* __restrict__ xvH,
                                                 const int* __restrict__ esrc) {
  int b = blockIdx.x;
  int tid = threadIdx.x;
  if (b < f.leanTotal) {
    // ---- lean Y_q gemm: Y = x_small @ Wl_q, h-only out ----
    int g = 0;
    #pragma unroll
    for (int i = 1; i < 5; ++i) if (i < f.nG && b >= f.gOff[i]) g = i;
    int blockRow = (b - f.gOff[g]) * 32;
    int lane = tid & 63, wave = tid >> 6;
    int quad = lane >> 4, lm = lane & 15;
    int wr = wave >> 1, wc = wave & 1;
    const _Float16* AH = f.gAH[g];
    const _Float16* AL = f.gAL[g];
    const _Float16* W = f.gW[g];
    int M = f.gM[g];
    int ar = blockRow + wr * 16 + lm;
    if (ar >= M) ar = M - 1;  // clamp (dup row ok)
    f32x4 acc[4];
    #pragma unroll
    for (int nt = 0; nt < 4; ++nt) acc[nt] = (f32x4){0.f, 0.f, 0.f, 0.f};
    for (int ks = 0; ks < 128; ks += 32) {
      f16x8 ah = *(const f16x8*)(AH + (size_t)ar * 128 + ks + quad * 8);
      f16x8 al = *(const f16x8*)(AL + (size_t)ar * 128 + ks + quad * 8);
      #pragma unroll
      for (int nt = 0; nt < 4; ++nt) {
        int n = wc * 64 + nt * 16 + lm;
        f16x8 bh = *(const f16x8*)(W + (size_t)n * 136 + ks + quad * 8);
        f16x8 bl = *(const f16x8*)(W + (size_t)(128 + n) * 136 + ks + quad * 8);
        acc[nt] = __builtin_amdgcn_mfma_f32_16x16x32_f16(ah, bh, acc[nt], 0, 0, 0);
        acc[nt] = __builtin_amdgcn_mfma_f32_16x16x32_f16(ah, bl, acc[nt], 0, 0, 0);
        acc[nt] = __builtin_amdgcn_mfma_f32_16x16x32_f16(al, bh, acc[nt], 0, 0, 0);
      }
    }
    _Float16* Y = f.gY[g];
    #pragma unroll
    for (int i = 0; i < 4; ++i) {
      int grow = blockRow + wr * 16 + quad * 4 + i;
      if (grow >= M) continue;
      #pragma unroll
      for (int nt = 0; nt < 4; ++nt)
        Y[(size_t)grow * 128 + wc * 64 + nt * 16 + lm] = (_Float16)acc[nt][i];
    }
    return;
  }
  // ---- agg_small ----
  b -= f.leanTotal;
  int t = 0;
  #pragma unroll
  for (int i = 1; i < 5; ++i) if (i < f.nAgg && b >= f.aOff[i]) t = i;
  int row = (b - f.aOff[t]) * 16 + (tid >> 4);
  if (row >= f.aM[t]) return;
  int q = tid & 15;
  const int* rp = f.rp[t];
  int e0 = rp[row], e1 = rp[row + 1];
  float a[8];
  #pragma unroll
  for (int j = 0; j < 8; ++j) a[j] = 0.f;
  int e = e0;
  for (; e + 4 <= e1; e += 4) {
    int s0 = esrc[e], s1 = esrc[e + 1], s2 = esrc[e + 2], s3 = esrc[e + 3];
    f16x8 v0 = *(const f16x8*)(xvH + (size_t)s0 * 128 + q * 8);
    f16x8 v1 = *(const f16x8*)(xvH + (size_t)s1 * 128 + q * 8);
    f16x8 v2 = *(const f16x8*)(xvH + (size_t)s2 * 128 + q * 8);
    f16x8 v3 = *(const f16x8*)(xvH + (size_t)s3 * 128 + q * 8);
    #pragma unroll
    for (int j = 0; j < 8; ++j)
      a[j] += ((float)v0[j] + (float)v1[j]) + ((float)v2[j] + (float)v3[j]);
  }
  for (; e < e1; ++e) {
    int s = esrc[e];
    f16x8 v = *(const f16x8*)(xvH + (size_t)s * 128 + q * 8);
    #pragma unroll
    for (int j = 0; j < 8; ++j) a[j] += (float)v[j];
  }
  float inv = (e1 > e0) ? 1.f / (float)(e1 - e0) : 0.f;
  f16x8 h, l;
  #pragma unroll
  for (int j = 0; j < 8; ++j) {
    float v = a[j] * inv;
    h[j] = (_Float16)v;
    l[j] = (_Float16)(v - (float)h[j]);
  }
  size_t o = (size_t)row * 128 + q * 8;
  *(f16x8*)(f.mH[t] + o) = h;
  *(f16x8*)(f.mL[t] + o) = l;
}

// ---------------- visit agg: single merged weighted loop (R12 body) --------
__global__ __launch_bounds__(256) void agg_visit(const int* __restrict__ mprefix,
                                                 const int2* __restrict__ mesrc,
                                                 const _Float16* __restrict__ YH,
                                                 _Float16* __restrict__ xvH,
                                                 _Float16* __restrict__ xvL, int doRelu) {
  int row = blockIdx.x * 16 + (threadIdx.x >> 4);
  if (row >= NVISIT) return;
  int q = threadIdx.x & 15;
  size_t o = (size_t)row * 128 + q * 8;
  f16x8 h0 = *(f16x8*)(xvH + o);
  f16x8 l0 = *(f16x8*)(xvL + o);
  float a[8];
  #pragma unroll
  for (int j = 0; j < 8; ++j) a[j] = (float)h0[j] + (float)l0[j];
  int e0 = mprefix[row], e1 = mprefix[row + 1];
  int e = e0;
  for (; e + 4 <= e1; e += 4) {
    int2 p0 = mesrc[e], p1 = mesrc[e + 1], p2 = mesrc[e + 2], p3 = mesrc[e + 3];
    f16x8 v0 = *(const f16x8*)(YH + (size_t)p0.x * 128 + q * 8);
    f16x8 v1 = *(const f16x8*)(YH + (size_t)p1.x * 128 + q * 8);
    f16x8 v2 = *(const f16x8*)(YH + (size_t)p2.x * 128 + q * 8);
    f16x8 v3 = *(const f16x8*)(YH + (size_t)p3.x * 128 + q * 8);
    float w0 = __int_as_float(p0.y), w1 = __int_as_float(p1.y);
    float w2 = __int_as_float(p2.y), w3 = __int_as_float(p3.y);
    #pragma unroll
    for (int j = 0; j < 8; ++j)
      a[j] += (w0 * (float)v0[j] + w1 * (float)v1[j]) +
              (w2 * (float)v2[j] + w3 * (float)v3[j]);
  }
  for (; e < e1; ++e) {
    int2 p = mesrc[e];
    f16x8 v = *(const f16x8*)(YH + (size_t)p.x * 128 + q * 8);
    float w = __int_as_float(p.y);
    #pragma unroll
    for (int j = 0; j < 8; ++j) a[j] += w * (float)v[j];
  }
  f16x8 h, l;
  #pragma unroll
  for (int j = 0; j < 8; ++j) {
    float v = doRelu ? fmaxf(a[j], 0.f) : a[j];
    h[j] = (_Float16)v;
    l[j] = (_Float16)(v - (float)h[j]);
  }
  *(f16x8*)(xvH + o) = h;
  *(f16x8*)(xvL + o) = l;
}

// ---------------- MFMA f16x3 GEMM, multi-task, split-plane A ---------------
__global__ __launch_bounds__(256, 2) void mgemm(MMeta mm) {
  int b = blockIdx.x;
  int ti = 0;
  for (int i = 1; i < mm.nTasks; ++i) if (b >= mm.t[i].blkOff) ti = i;
  MTask tk = mm.t[ti];
  int blockRow = (b - tk.blkOff) * 128;
  int Kpad = tk.K + 8;

  __shared__ _Float16 Ash[2][128][72];
  int tid = threadIdx.x;
  int wave = tid >> 6, lane = tid & 63;
  int quad = lane >> 4, lm = lane & 15;
  int wr = wave >> 1, wc = wave & 1;

  f32x4 acc[4][4];
  #pragma unroll
  for (int i = 0; i < 4; ++i)
    #pragma unroll
    for (int j = 0; j < 4; ++j) acc[i][j] = (f32x4){0.f, 0.f, 0.f, 0.f};

  const _Float16* wrowH[4];
  const _Float16* wrowL[4];
  #pragma unroll
  for (int nt = 0; nt < 4; ++nt) {
    int n = wc * 64 + nt * 16 + lm;
    wrowH[nt] = tk.W + (size_t)n * Kpad;
    wrowL[nt] = tk.W + (size_t)(128 + n) * Kpad;
  }

  int sr = tid >> 1, sk = (tid & 1) * 32;
  int gr = blockRow + sr; if (gr >= tk.M) gr = tk.M - 1;  // clamp (dup row ok)
  for (int k0 = 0; k0 < tk.K; k0 += 64) {
    const _Float16* AH = (k0 < 128) ? tk.AH0 : tk.AH1;
    const _Float16* AL = (k0 < 128) ? tk.AL0 : tk.AL1;
    size_t abase = (size_t)gr * 128 + (k0 & 127) + sk;
    #pragma unroll
    for (int c = 0; c < 4; ++c) {
      *(f16x8*)&Ash[0][sr][sk + c * 8] = *(const f16x8*)(AH + abase + c * 8);
      *(f16x8*)&Ash[1][sr][sk + c * 8] = *(const f16x8*)(AL + abase + c * 8);
    }
    __syncthreads();
    #pragma unroll
    for (int ks = 0; ks < 64; ks += 32) {
      int kf = k0 + ks + quad * 8;
      f16x8 bh[4], bl[4];
      #pragma unroll
      for (int nt = 0; nt < 4; ++nt) {
        bh[nt] = *(const f16x8*)(wrowH[nt] + kf);
        bl[nt] = *(const f16x8*)(wrowL[nt] + kf);
      }
      #pragma unroll
      for (int mt = 0; mt < 4; ++mt) {
        int r = wr * 64 + mt * 16 + lm;
        f16x8 ah = *(const f16x8*)&Ash[0][r][ks + quad * 8];
        f16x8 al = *(const f16x8*)&Ash[1][r][ks + quad * 8];
        #pragma unroll
        for (int nt = 0; nt < 4; ++nt) {
          acc[mt][nt] = __builtin_amdgcn_mfma_f32_16x16x32_f16(ah, bh[nt], acc[mt][nt], 0, 0, 0);
          acc[mt][nt] = __builtin_amdgcn_mfma_f32_16x16x32_f16(ah, bl[nt], acc[mt][nt], 0, 0, 0);
          acc[mt][nt] = __builtin_amdgcn_mfma_f32_16x16x32_f16(al, bh[nt], acc[mt][nt], 0, 0, 0);
        }
      }
    }
    __syncthreads();
  }

  float bv[4];
  #pragma unroll
  for (int nt = 0; nt < 4; ++nt)
    bv[nt] = tk.bias ? tk.bias[wc * 64 + nt * 16 + lm] : 0.f;
  #pragma unroll
  for (int mt = 0; mt < 4; ++mt) {
    #pragma unroll
    for (int i = 0; i < 4; ++i) {
      int grow = blockRow + wr * 64 + mt * 16 + quad * 4 + i;
      if (grow >= tk.M) continue;
      size_t ob = (size_t)grow * 128 + wc * 64 + lm;
      #pragma unroll
      for (int nt = 0; nt < 4; ++nt) {
        float v = acc[mt][nt][i] + bv[nt];
        if (tk.relu) v = fmaxf(v, 0.f);
        _Float16 h = (_Float16)v;
        tk.outH[ob + nt * 16] = h;
        if (tk.outL) tk.outL[ob + nt * 16] = (_Float16)(v - (float)h);
      }
    }
  }
}

// ---------------- factored classifier edge pass ----------------------------
__global__ __launch_bounds__(256) void cls_edge(
    const _Float16* __restrict__ UH, const _Float16* __restrict__ UL,
    const _Float16* __restrict__ VH, const _Float16* __restrict__ VL,
    const int* __restrict__ eli, const float* __restrict__ w2,
    const float* __restrict__ b2, const float* __restrict__ y,
    float* __restrict__ lossOut, float* __restrict__ pred, int M) {
  __shared__ float lsum[4];
  int tid = threadIdx.x;
  int q = tid & 15;
  int lane = tid & 63;
  float w2v[8];
  #pragma unroll
  for (int j = 0; j < 8; ++j) w2v[j] = w2[q * 8 + j];
  float bias = b2[0];
  float lacc = 0.f;
  int e0 = blockIdx.x * 128 + (tid >> 4);
  #pragma unroll
  for (int p = 0; p < 8; ++p) {
    int e = e0 + p * 16;
    if (e < M) {
      int vi = eli[e], di = eli[M + e];
      size_t uo = (size_t)vi * 128 + q * 8;
      size_t vo = (size_t)di * 128 + q * 8;
      f16x8 uh = *(const f16x8*)(UH + uo);
      f16x8 ul = *(const f16x8*)(UL + uo);
      f16x8 vh = *(const f16x8*)(VH + vo);
      f16x8 vl = *(const f16x8*)(VL + vo);
      float part = 0.f;
      #pragma unroll
      for (int j = 0; j < 8; ++j) {
        float t = ((float)uh[j] + (float)ul[j]) + ((float)vh[j] + (float)vl[j]);
        part += fmaxf(t, 0.f) * w2v[j];
      }
      part += __shfl_xor(part, 1);
      part += __shfl_xor(part, 2);
      part += __shfl_xor(part, 4);
      part += __shfl_xor(part, 8);
      if (q == 0) {
        float z = part + bias;
        pred[e] = z;
        lacc += fmaxf(z, 0.f) + log1pf(expf(-fabsf(z))) - z * y[e];
      }
    }
  }
  lacc += __shfl_xor(lacc, 16);
  lacc += __shfl_xor(lacc, 32);
  if (lane == 0) lsum[tid >> 6] = lacc;
  __syncthreads();
  if (tid == 0)
    atomicAdd(lossOut, (lsum[0] + lsum[1] + lsum[2] + lsum[3]) * (1.0f / 200000.0f));
}

// ---------------------------------------------------------------------------
extern "C" void kernel_launch(void* const* d_in, const int* in_sizes, int n_in,
                              void* d_out, int out_size, void* d_ws, size_t ws_size,
                              hipStream_t stream) {
  static const int kRows[6] = {20000, 100000, 4000, 8000, 10000, 4000};
  static const int kOff[6]  = {0, 20000, 120000, 124000, 132000, 142000};
  static const int kSmallT[5]   = {0, 2, 3, 4, 5};
  static const int kInRel[5]    = {1, 2, 4, 6, 8};
  static const int kCbcIn[5]    = {100000, 120000, 224000, 332000, 442000};
  static const int kYOff[5]     = {0, 20000, 24000, 32000, 42000};
  static const int kBOff[5]     = {0, 157, 189, 252, 331};
  static const int kAggOff[5]   = {0, 1250, 1500, 2000, 2625};   // 16-row blocks
  static const int kLeanOff[5]  = {0, 625, 750, 1000, 1313};     // 32-row blocks
  const int kAggTotal = 2875, kLeanTotal = 1438;
  // bucket config (rel order: pv,vp,vs,sv,vpr,prv,vd,dv,vdr,drv)
  static const int kCbcA[NREL]  = {0, 100000, 120000, 124000, 224000,
                                   232000, 332000, 342000, 442000, 446000};
  static const int kEhA[NREL]   = {100000, 100000, 300000, 300000, 200000,
                                   200000, 250000, 250000, 300000, 300000};
  static const int kNdst[NREL]  = {100000, 20000, 4000, 100000, 8000,
                                   100000, 10000, 100000, 4000, 100000};
  static const int kSh[NREL]    = {11, 9, 5, 10, 7, 10, 7, 10, 5, 10};
  static const int kNB[NREL]    = {49, 40, 125, 98, 63, 98, 79, 98, 125, 98};
  static const int kBB[NREL]    = {0, 49, 89, 214, 312, 375, 473, 552, 650, 775};

  const float* W_l = (const float*)d_in[22];
  const float* b_l = (const float*)d_in[23];
  const float* W_r = (const float*)d_in[24];
  const float* cw1 = (const float*)d_in[25];
  const float* cb1 = (const float*)d_in[26];
  const float* cw2 = (const float*)d_in[27];
  const float* cb2 = (const float*)d_in[28];
  const int* eli = (const int*)d_in[29];
  const float* ylab = (const float*)d_in[30];

  // workspace layout
  _Float16* H = (_Float16*)d_ws;                 // XELEMS
  _Float16* L = H + XELEMS;                      // XELEMS
  _Float16* meanH = L + XELEMS;                  // SELEMS
  _Float16* meanL = meanH + SELEMS;              // SELEMS
  _Float16* YH = meanL + SELEMS;                 // SELEMS
  _Float16* Wt = YH + SELEMS;                    // WT_ELEMS
  int* prefix = (int*)(Wt + WT_ELEMS);           // 546,004
  int* counts = prefix + 546004;                 // 546,000 (reused as mprefix)
  int* esrc = counts + NCOUNTS;                  // 2,300,000
  int* partials = esrc + NEDGES;                 // 1,024
  float* visitSumB = (float*)(partials + 1024);  // 512
  int* bcur = (int*)(visitSumB + 512);           // NBKT (+pad)
  int* bdata = bcur + 1024;                      // NBKT * BCAP ints (reused as mesrc)

  int* mprefix = counts;        // free after scan3
  int2* mesrc = (int2*)bdata;   // free after bkt_p2b

  // classifier U/V tables (alive only after layer-3; reuse dead regions)
  _Float16* UH = meanH;
  _Float16* VH = meanH + (size_t)NVISIT * 128;
  _Float16* VL = VH + (size_t)4000 * 128;
  _Float16* UL = (_Float16*)prefix;

  BkMeta bm;
  for (int r = 0; r < NREL; ++r) {
    bm.ei[r] = (const int*)d_in[12 + r];
    bm.E[r] = kEhA[r];
    bm.cbc[r] = kCbcA[r];
    bm.ndst[r] = kNdst[r];
    bm.sh[r] = kSh[r];
    bm.bb[r] = kBB[r];
    bm.nb[r] = kNB[r];
  }

  hipMemsetAsync(bcur, 0, NBKT * sizeof(int), stream);
  hipMemsetAsync(d_out, 0, sizeof(float), stream);

  prep_split<<<(1081856 + 255) / 256, 256, 0, stream>>>(W_l, b_l, W_r, cw1, Wt, visitSumB);

  GatherMeta gm;
  for (int t = 0; t < 6; ++t) {
    gm.nid[t] = (const int*)d_in[2 * t];
    gm.emb[t] = (const float*)d_in[2 * t + 1];
    gm.rows[t] = kRows[t];
    gm.off[t] = kOff[t];
  }
  conv0<<<dim3(6250, 6), 256, 0, stream>>>(gm, H, L);

  // CSR build
  bkt_p1<<<dim3(74, NREL), 256, 0, stream>>>(bm, bcur, bdata);
  bkt_p2a<<<dim3(NBKT), 256, 0, stream>>>(bm, bcur, bdata, counts);
  scan1<<<534, 1024, 0, stream>>>(counts, partials);
  scan2<<<1, 1024, 0, stream>>>(partials, 534);
  scan3<<<534, 1024, 0, stream>>>(counts, prefix, partials);
  bkt_p2b<<<dim3(NBKT), 256, 0, stream>>>(bm, bcur, bdata, prefix, esrc);
  merge_visit<<<dim3((NVISIT + 255) / 256), 256, 0, stream>>>(prefix, esrc, mprefix, mesrc);

  _Float16* xvH = H + (size_t)kOff[1] * 128;
  _Float16* xvL = L + (size_t)kOff[1] * 128;

  for (int l = 0; l < 4; ++l) {
    int doRelu = (l < 3);
    int last = (l == 3);
    _Float16* LW = Wt + (size_t)l * PLW;

    // F1: lean Y_q (first) || agg_small
    F1Meta f1;
    f1.leanTotal = kLeanTotal;
    for (int q = 0; q < 5; ++q) {
      size_t so = (size_t)kOff[kSmallT[q]] * 128;
      f1.gAH[q] = H + so;
      f1.gAL[q] = L + so;
      f1.gW[q] = LW + 337920 + (size_t)q * 34816;
      f1.gY[q] = YH + (size_t)kYOff[q] * 128;
      f1.gM[q] = kRows[kSmallT[q]];
      f1.gOff[q] = kLeanOff[q];
    }
    f1.nG = 5;
    int aggTotal;
    if (!last) {
      for (int t = 0; t < 5; ++t) {
        f1.rp[t] = prefix + kCbcIn[t];
        f1.mH[t] = meanH + (size_t)kYOff[t] * 128;
        f1.mL[t] = meanL + (size_t)kYOff[t] * 128;
        f1.aM[t] = kRows[kSmallT[t]];
        f1.aOff[t] = kAggOff[t];
      }
      f1.nAgg = 5;
      aggTotal = kAggTotal;
    } else {
      f1.rp[0] = prefix + kCbcIn[4];
      f1.mH[0] = meanH + (size_t)kYOff[4] * 128;
      f1.mL[0] = meanL + (size_t)kYOff[4] * 128;
      f1.aM[0] = 4000;
      f1.aOff[0] = 0;
      for (int t = 1; t < 5; ++t) { f1.rp[t] = nullptr; f1.mH[t] = nullptr; f1.mL[t] = nullptr; f1.aM[t] = 0; f1.aOff[t] = 0; }
      f1.nAgg = 1;
      aggTotal = 250;
    }
    fused1<<<dim3(kLeanTotal + aggTotal), 256, 0, stream>>>(f1, xvH, esrc);

    // F2: m1 (small-dst [mean|x_old]@[Wl;Wr]) || m2_visit (in-place), one grid
    MMeta m;
    if (!last) {
      m.nTasks = 6;
      for (int t = 0; t < 5; ++t) {
        size_t mo = (size_t)kYOff[t] * 128;
        size_t so = (size_t)kOff[kSmallT[t]] * 128;
        m.t[t].AH0 = meanH + mo; m.t[t].AL0 = meanL + mo;
        m.t[t].AH1 = H + so;     m.t[t].AL1 = L + so;
        m.t[t].W = LW + (size_t)t * 67584;
        m.t[t].bias = b_l + (size_t)(l * 10 + kInRel[t]) * 128;
        m.t[t].outH = H + so;    m.t[t].outL = L + so;
        m.t[t].M = kRows[kSmallT[t]];
        m.t[t].blkOff = kBOff[t];
        m.t[t].K = 256;
        m.t[t].relu = doRelu;
      }
      m.t[5].AH0 = xvH; m.t[5].AL0 = xvL;
      m.t[5].AH1 = nullptr; m.t[5].AL1 = nullptr;
      m.t[5].W = LW + 512000;
      m.t[5].bias = visitSumB + l * 128;
      m.t[5].outH = xvH; m.t[5].outL = xvL;   // in-place (block-local rows)
      m.t[5].M = NVISIT;
      m.t[5].blkOff = 363;
      m.t[5].K = 128;
      m.t[5].relu = 0;
      mgemm<<<dim3(363 + 782), 256, 0, stream>>>(m);
    } else {
      size_t mo = (size_t)kYOff[4] * 128;
      size_t so = (size_t)kOff[5] * 128;   // drug
      m.nTasks = 2;
      m.t[0].AH0 = meanH + mo; m.t[0].AL0 = meanL + mo;
      m.t[0].AH1 = H + so;     m.t[0].AL1 = L + so;
      m.t[0].W = LW + (size_t)4 * 67584;
      m.t[0].bias = b_l + (size_t)(l * 10 + kInRel[4]) * 128;
      m.t[0].outH = H + so;    m.t[0].outL = L + so;
      m.t[0].M = 4000;
      m.t[0].blkOff = 0;
      m.t[0].K = 256;
      m.t[0].relu = 0;
      m.t[1].AH0 = xvH; m.t[1].AL0 = xvL;
      m.t[1].AH1 = nullptr; m.t[1].AL1 = nullptr;
      m.t[1].W = LW + 512000;
      m.t[1].bias = visitSumB + l * 128;
      m.t[1].outH = xvH; m.t[1].outL = xvL;
      m.t[1].M = NVISIT;
      m.t[1].blkOff = 32;
      m.t[1].K = 128;
      m.t[1].relu = 0;
      mgemm<<<dim3(32 + 782), 256, 0, stream>>>(m);
    }

    // F3: x_v(H,L) += weighted merged gather of YH; relu; re-split
    agg_visit<<<dim3(6250), 256, 0, stream>>>(mprefix, mesrc, YH, xvH, xvL, doRelu);
  }

  // classifier precompute: U = xv@W1top + b1 (split), V = xd@W1bot (split)
  MMeta muv;
  muv.nTasks = 2;
  muv.t[0].AH0 = xvH; muv.t[0].AL0 = xvL;
  muv.t[0].AH1 = nullptr; muv.t[0].AL1 = nullptr;
  muv.t[0].W = Wt + (size_t)4 * PLW;
  muv.t[0].bias = cb1;
  muv.t[0].outH = UH; muv.t[0].outL = UL;
  muv.t[0].M = NVISIT;
  muv.t[0].blkOff = 0;
  muv.t[0].K = 128;
  muv.t[0].relu = 0;
  muv.t[1].AH0 = H + (size_t)kOff[5] * 128; muv.t[1].AL0 = L + (size_t)kOff[5] * 128;
  muv.t[1].AH1 = nullptr; muv.t[1].AL1 = nullptr;
  muv.t[1].W = Wt + (size_t)4 * PLW + 34816;
  muv.t[1].bias = nullptr;
  muv.t[1].outH = VH; muv.t[1].outL = VL;
  muv.t[1].M = 4000;
  muv.t[1].blkOff = 782;
  muv.t[1].K = 128;
  muv.t[1].relu = 0;
  mgemm<<<dim3(782 + 32), 256, 0, stream>>>(muv);

  const int ML = 200000;
  cls_edge<<<dim3((ML + 127) / 128), 256, 0, stream>>>(
      UH, UL, VH, VL, eli, cw2, cb2, ylab,
      (float*)d_out, (float*)d_out + 1, ML);
}

// Round 10
// 909.069 us; speedup vs baseline: 1.0859x; 1.0140x over previous
//
#include <hip/hip_runtime.h>
#include <cmath>

// ---------------------------------------------------------------------------
// Hetero-SAGE GNN (4 layers, 10 relations, D=128) + edge classifier.
// R19: revert to R16's proven schedule (911us): fused1 with AGG-FIRST block
//   order (R18's lean-first A/B: 64->70us, occ 62->55% — LPT wins: long agg
//   blocks must dispatch first, short MFMA blocks backfill the drain tail).
//   NEW: preamble collapsed to ONE kernel pre_all = conv0 (37500 blks, first)
//   || prep_split (4226) || bkt_p1 (740) — all mutually independent; removes
//   two full-device launch boundaries (~55us+gaps -> ~35us).
// R16: fused1 (agg_small || lean Yq), F2=mgemm{m1 x5, visit}, F3=agg_visit.
// R11: factored classifier. R10: merged weighted visit-CSR. R9: bucket-sort
//   CSR build. R8: split-f16 H/L planes, f16x3 MFMA GEMMs, layer-3 pruning.
// ---------------------------------------------------------------------------

typedef _Float16 f16x8 __attribute__((ext_vector_type(8)));
typedef float f32x4 __attribute__((ext_vector_type(4)));

#define NREL 10
#define NCOUNTS 546000
#define NEDGES  2300000
#define NVISIT  100000
#define NVEDGES 1150000
#define PLW 546816
#define WT_ELEMS (4 * PLW + 69632)
#define XELEMS 18688000UL   // 146000*128
#define SELEMS 5888000UL    // 46000*128
#define NBKT 873
#define BCAP 5056

struct BkMeta {
  const int* ei[NREL]; int E[NREL]; int cbc[NREL]; int ndst[NREL];
  int sh[NREL]; int bb[NREL]; int nb[NREL];
};
struct PreMeta {
  const float* emb[6]; const int* nid[6]; int rows[6]; int off[6];
  const float* W_l; const float* b_l; const float* W_r; const float* cw1;
  _Float16* Wt; float* visitSumB;
};
struct MTask {
  const _Float16* AH0; const _Float16* AL0;  // k in [0,128)
  const _Float16* AH1; const _Float16* AL1;  // k in [128,256)
  const _Float16* W;                         // [2][128][Kpad] h then l plane
  const float* bias;                         // nullable
  _Float16* outH; _Float16* outL;            // outL nullable (h-only output)
  int M, blkOff, K, relu;
};
struct MMeta { MTask t[6]; int nTasks; };
// F1: agg_small blocks first (LPT), then lean Y_q gemm blocks
struct F1Meta {
  const int* rp[5]; _Float16* mH[5]; _Float16* mL[5]; int aM[5]; int aOff[5];
  int nAgg; int aggTotal;
  const _Float16* gAH[5]; const _Float16* gAL[5]; const _Float16* gW[5];
  _Float16* gY[5]; int gM[5]; int gOff[5]; int nG;
};

// ---------------- pre_all: conv0 || prep_split || bkt_p1 -------------------
// blocks [0,37500): conv0 emb->split H/L (t = b/6250)
// blocks [37500,41726): prep_split (weight split/transpose)
// blocks [41726,42466): bkt_p1 (r = fb/74, bx = fb%74)
__global__ __launch_bounds__(256) void pre_all(PreMeta pm, BkMeta bm,
                                               _Float16* __restrict__ H,
                                               _Float16* __restrict__ L,
                                               int* __restrict__ bcur,
                                               int* __restrict__ bdata) {
  __shared__ int cnt[128];
  __shared__ int base[128];
  __shared__ unsigned short rnk[4096];
  int b = blockIdx.x;
  int tid = threadIdx.x;
  if (b < 37500) {
    // ---- conv0 ----
    int t = b / 6250;
    int i = (b % 6250) * 256 + tid;
    if (i >= pm.rows[t] * 16) return;
    int row = i >> 4, q = i & 15;
    int s = pm.nid[t][row];
    const float* p = pm.emb[t] + (size_t)s * 128 + q * 8;
    float4 v0 = *(const float4*)p;
    float4 v1 = *(const float4*)(p + 4);
    float v[8] = {v0.x, v0.y, v0.z, v0.w, v1.x, v1.y, v1.z, v1.w};
    f16x8 h, l;
    #pragma unroll
    for (int j = 0; j < 8; ++j) {
      h[j] = (_Float16)v[j];
      l[j] = (_Float16)(v[j] - (float)h[j]);
    }
    size_t o = (size_t)(pm.off[t] + row) * 128 + q * 8;
    *(f16x8*)(H + o) = h;
    *(f16x8*)(L + o) = l;
    return;
  }
  if (b < 41726) {
    // ---- prep_split ----
    const int visitRel[5] = {0, 3, 5, 7, 9};
    const int inRel[5] = {1, 2, 4, 6, 8};
    int gid = (b - 37500) * 256 + tid;
    if (gid < 1048576) {
      int l = gid >> 18, o = gid & 262143;
      float val; size_t wbase; int n, k, Kpad;
      if (o < 163840) {          // small stacks, K=256
        int t = o >> 15, e = o & 32767;
        k = e >> 7; n = e & 127; Kpad = 264;
        int r = inRel[t];
        val = (k < 128) ? pm.W_l[(size_t)(l * 10 + r) * 16384 + k * 128 + n]
                        : pm.W_r[(size_t)(l * 10 + r) * 16384 + (k - 128) * 128 + n];
        wbase = (size_t)l * PLW + t * 67584;
      } else if (o < 245760) {   // trans Wl, K=128
        int q = (o - 163840) >> 14, e = (o - 163840) & 16383;
        k = e >> 7; n = e & 127; Kpad = 136;
        val = pm.W_l[(size_t)(l * 10 + visitRel[q]) * 16384 + k * 128 + n];
        wbase = (size_t)l * PLW + 337920 + q * 34816;
      } else {                   // SumWr, K=128
        int e = o - 245760;
        k = e >> 7; n = e & 127; Kpad = 136;
        val = 0.f;
        #pragma unroll
        for (int q = 0; q < 5; ++q)
          val += pm.W_r[(size_t)(l * 10 + visitRel[q]) * 16384 + k * 128 + n];
        wbase = (size_t)l * PLW + 512000;
      }
      _Float16 h = (_Float16)val;
      _Float16 lo = (_Float16)(val - (float)h);
      pm.Wt[wbase + (size_t)n * Kpad + k] = h;
      pm.Wt[wbase + (size_t)(128 + n) * Kpad + k] = lo;
    } else if (gid < 1081344) {  // cls W1 -> two K=128 split layouts (top|bot)
      int e = gid - 1048576;
      int k = e >> 7, n = e & 127;
      float val = pm.cw1[(size_t)k * 128 + n];
      _Float16 h = (_Float16)val;
      _Float16 lo = (_Float16)(val - (float)h);
      size_t wbase = (size_t)4 * PLW + (k < 128 ? 0 : 34816);
      int kk = k & 127;
      pm.Wt[wbase + (size_t)n * 136 + kk] = h;
      pm.Wt[wbase + (size_t)(128 + n) * 136 + kk] = lo;
    } else if (gid < 1081856) {  // visit summed bias
      int e = gid - 1081344;
      int l = e >> 7, c = e & 127;
      float val = 0.f;
      #pragma unroll
      for (int q = 0; q < 5; ++q) val += pm.b_l[(l * 10 + visitRel[q]) * 128 + c];
      pm.visitSumB[e] = val;
    }
    return;
  }
  // ---- bkt_p1 ----
  int fb = b - 41726;
  int r = fb / 74;
  int bx = fb - r * 74;
  int E = bm.E[r], sh = bm.sh[r], bb = bm.bb[r], nb = bm.nb[r];
  if (tid < 128) cnt[tid] = 0;
  __syncthreads();
  int e0 = bx * 4096;
  if (e0 >= E) return;
  const int* dstp = bm.ei[r] + E;
  const int* srcp = bm.ei[r];
  #pragma unroll
  for (int i = 0; i < 16; ++i) {
    int e = e0 + i * 256 + tid;
    if (e < E) {
      int bk = dstp[e] >> sh;
      rnk[i * 256 + tid] = (unsigned short)atomicAdd(&cnt[bk], 1);
    }
  }
  __syncthreads();
  if (tid < nb && cnt[tid] > 0) base[tid] = atomicAdd(&bcur[bb + tid], cnt[tid]);
  __syncthreads();
  #pragma unroll
  for (int i = 0; i < 16; ++i) {
    int e = e0 + i * 256 + tid;
    if (e < E) {
      int d = dstp[e];
      int bk = d >> sh;
      int pos = base[bk] + (int)rnk[i * 256 + tid];
      if (pos < BCAP)
        bdata[(size_t)(bb + bk) * BCAP + pos] = ((d & ((1 << sh) - 1)) << 17) | srcp[e];
    }
  }
}

// p2a: per-bucket LDS hist -> coalesced counts
__global__ __launch_bounds__(256) void bkt_p2a(BkMeta bm, const int* __restrict__ bcur,
                                               const int* __restrict__ bdata,
                                               int* __restrict__ counts) {
  __shared__ int hist[2048];
  int g = blockIdx.x;
  int r = 0;
  #pragma unroll
  for (int i = 1; i < NREL; ++i) if (g >= bm.bb[i]) r = i;
  int lb = g - bm.bb[r];
  int sh = bm.sh[r], dpb = 1 << sh;
  int tid = threadIdx.x;
  for (int d = tid; d < dpb; d += 256) hist[d] = 0;
  __syncthreads();
  int cnt = bcur[g]; if (cnt > BCAP) cnt = BCAP;
  const int* bd = bdata + (size_t)g * BCAP;
  for (int i = tid; i < cnt; i += 256) atomicAdd(&hist[((unsigned)bd[i]) >> 17], 1);
  __syncthreads();
  int dBase = lb << sh;
  int dMax = bm.ndst[r] - dBase; if (dMax > dpb) dMax = dpb;
  for (int d = tid; d < dMax; d += 256) counts[bm.cbc[r] + dBase + d] = hist[d];
}

// ---------------- global scan (3-phase) ------------------------------------
__global__ __launch_bounds__(1024) void scan1(const int* __restrict__ counts,
                                              int* __restrict__ partials) {
  __shared__ int s[1024];
  int i = blockIdx.x * 1024 + threadIdx.x;
  s[threadIdx.x] = (i < NCOUNTS) ? counts[i] : 0;
  __syncthreads();
  for (int off = 512; off > 0; off >>= 1) {
    if (threadIdx.x < off) s[threadIdx.x] += s[threadIdx.x + off];
    __syncthreads();
  }
  if (threadIdx.x == 0) partials[blockIdx.x] = s[0];
}

__global__ __launch_bounds__(1024) void scan2(int* __restrict__ partials, int nb) {
  __shared__ int s[1024];
  int t = threadIdx.x;
  int v = (t < nb) ? partials[t] : 0;
  s[t] = v;
  __syncthreads();
  for (int off = 1; off < 1024; off <<= 1) {
    int add = (t >= off) ? s[t - off] : 0;
    __syncthreads();
    s[t] += add;
    __syncthreads();
  }
  if (t < nb) partials[t] = s[t] - v;  // exclusive
}

__global__ __launch_bounds__(1024) void scan3(const int* __restrict__ counts,
                                              int* __restrict__ prefix,
                                              const int* __restrict__ partials) {
  __shared__ int s[1024];
  int t = threadIdx.x;
  int i = blockIdx.x * 1024 + t;
  int v = (i < NCOUNTS) ? counts[i] : 0;
  s[t] = v;
  __syncthreads();
  for (int off = 1; off < 1024; off <<= 1) {
    int add = (t >= off) ? s[t - off] : 0;
    __syncthreads();
    s[t] += add;
    __syncthreads();
  }
  int P = partials[blockIdx.x] + s[t] - v;
  if (i < NCOUNTS) prefix[i] = P;
  if (blockIdx.x == 0 && t == 0) prefix[NCOUNTS] = NEDGES;
}

// p2b: per-bucket LDS counting sort -> contiguous coalesced esrc run
__global__ __launch_bounds__(256) void bkt_p2b(BkMeta bm, const int* __restrict__ bcur,
                                               const int* __restrict__ bdata,
                                               const int* __restrict__ prefix,
                                               int* __restrict__ esrc) {
  __shared__ int pk[BCAP];
  __shared__ int srt[BCAP];
  __shared__ int cur[2048];
  __shared__ int part[256];
  __shared__ int baseSh;
  int g = blockIdx.x;
  int r = 0;
  #pragma unroll
  for (int i = 1; i < NREL; ++i) if (g >= bm.bb[i]) r = i;
  int lb = g - bm.bb[r];
  int sh = bm.sh[r], dpb = 1 << sh;
  int tid = threadIdx.x;
  int cnt = bcur[g]; if (cnt > BCAP) cnt = BCAP;
  const int* bd = bdata + (size_t)g * BCAP;
  for (int d = tid; d < dpb; d += 256) cur[d] = 0;
  for (int i = tid; i < cnt; i += 256) pk[i] = bd[i];
  __syncthreads();
  for (int i = tid; i < cnt; i += 256) atomicAdd(&cur[((unsigned)pk[i]) >> 17], 1);
  __syncthreads();
  int seg = (dpb + 255) >> 8;
  int s = 0;
  int b0 = tid * seg;
  for (int j = 0; j < seg; ++j) {
    int idx = b0 + j;
    if (idx < dpb) { int v = cur[idx]; cur[idx] = s; s += v; }
  }
  part[tid] = s;
  __syncthreads();
  for (int off = 1; off < 256; off <<= 1) {
    int add = (tid >= off) ? part[tid - off] : 0;
    __syncthreads();
    part[tid] += add;
    __syncthreads();
  }
  int myoff = part[tid] - s;
  for (int j = 0; j < seg; ++j) {
    int idx = b0 + j;
    if (idx < dpb) cur[idx] += myoff;
  }
  if (tid == 0) baseSh = prefix[bm.cbc[r] + (lb << sh)];
  __syncthreads();
  for (int i = tid; i < cnt; i += 256) {
    int p = pk[i];
    int pos = atomicAdd(&cur[((unsigned)p) >> 17], 1);
    srt[pos] = p & 0x1FFFF;
  }
  __syncthreads();
  int base = baseSh;
  for (int i = tid; i < cnt; i += 256) esrc[base + i] = srt[i];
}

// ---------------- merged weighted visit CSR (built once) -------------------
__global__ __launch_bounds__(256) void merge_visit(const int* __restrict__ prefix,
                                                   const int* __restrict__ esrc,
                                                   int* __restrict__ mprefix,
                                                   int2* __restrict__ mesrc) {
  const int cbc[5]  = {0, 124000, 232000, 342000, 446000};
  const int yoff[5] = {0, 20000, 24000, 32000, 42000};
  int v = blockIdx.x * 256 + threadIdx.x;
  if (v >= NVISIT) return;
  int e0[5], e1[5];
  int base = 0;
  #pragma unroll
  for (int q = 0; q < 5; ++q) {
    e0[q] = prefix[cbc[q] + v];
    e1[q] = prefix[cbc[q] + v + 1];
    base += e0[q] - prefix[cbc[q]];
  }
  mprefix[v] = base;
  if (v == NVISIT - 1) {
    int t = base;
    #pragma unroll
    for (int q = 0; q < 5; ++q) t += e1[q] - e0[q];
    mprefix[NVISIT] = t;
  }
  int pos = base;
  #pragma unroll
  for (int q = 0; q < 5; ++q) {
    int d = e1[q] - e0[q];
    if (d > 0) {
      int wb = __float_as_int(1.f / (float)d);
      for (int e = e0[q]; e < e1[q]; ++e)
        mesrc[pos++] = make_int2(yoff[q] + esrc[e], wb);
    }
  }
}

// ---------------- F1: agg_small (first, LPT) || lean no-LDS Y_q GEMM -------
__global__ __launch_bounds__(256, 8) void fused1(F1Meta f,
                                                 const _Float16* __restrict__ xvH,
                                                 const int* __restrict__ esrc) {
  int b = blockIdx.x;
  int tid = threadIdx.x;
  if (b < f.aggTotal) {
    int t = 0;
    #pragma unroll
    for (int i = 1; i < 5; ++i) if (i < f.nAgg && b >= f.aOff[i]) t = i;
    int row = (b - f.aOff[t]) * 16 + (tid >> 4);
    if (row >= f.aM[t]) return;
    int q = tid & 15;
    const int* rp = f.rp[t];
    int e0 = rp[row], e1 = rp[row + 1];
    float a[8];
    #pragma unroll
    for (int j = 0; j < 8; ++j) a[j] = 0.f;
    int e = e0;
    for (; e + 4 <= e1; e += 4) {
      int s0 = esrc[e], s1 = esrc[e + 1], s2 = esrc[e + 2], s3 = esrc[e + 3];
      f16x8 v0 = *(const f16x8*)(xvH + (size_t)s0 * 128 + q * 8);
      f16x8 v1 = *(const f16x8*)(xvH + (size_t)s1 * 128 + q * 8);
      f16x8 v2 = *(const f16x8*)(xvH + (size_t)s2 * 128 + q * 8);
      f16x8 v3 = *(const f16x8*)(xvH + (size_t)s3 * 128 + q * 8);
      #pragma unroll
      for (int j = 0; j < 8; ++j)
        a[j] += ((float)v0[j] + (float)v1[j]) + ((float)v2[j] + (float)v3[j]);
    }
    for (; e < e1; ++e) {
      int s = esrc[e];
      f16x8 v = *(const f16x8*)(xvH + (size_t)s * 128 + q * 8);
      #pragma unroll
      for (int j = 0; j < 8; ++j) a[j] += (float)v[j];
    }
    float inv = (e1 > e0) ? 1.f / (float)(e1 - e0) : 0.f;
    f16x8 h, l;
    #pragma unroll
    for (int j = 0; j < 8; ++j) {
      float v = a[j] * inv;
      h[j] = (_Float16)v;
      l[j] = (_Float16)(v - (float)h[j]);
    }
    size_t o = (size_t)row * 128 + q * 8;
    *(f16x8*)(f.mH[t] + o) = h;
    *(f16x8*)(f.mL[t] + o) = l;
    return;
  }
  // ---- lean Y_q gemm ----
  b -= f.aggTotal;
  int g = 0;
  #pragma unroll
  for (int i = 1; i < 5; ++i) if (i < f.nG && b >= f.gOff[i]) g = i;
  int blockRow = (b - f.gOff[g]) * 32;
  int lane = tid & 63, wave = tid >> 6;
  int quad = lane >> 4, lm = lane & 15;
  int wr = wave >> 1, wc = wave & 1;
  const _Float16* AH = f.gAH[g];
  const _Float16* AL = f.gAL[g];
  const _Float16* W = f.gW[g];
  int M = f.gM[g];
  int ar = blockRow + wr * 16 + lm;
  if (ar >= M) ar = M - 1;  // clamp (dup row ok)
  f32x4 acc[4];
  #pragma unroll
  for (int nt = 0; nt < 4; ++nt) acc[nt] = (f32x4){0.f, 0.f, 0.f, 0.f};
  for (int ks = 0; ks < 128; ks += 32) {
    f16x8 ah = *(const f16x8*)(AH + (size_t)ar * 128 + ks + quad * 8);
    f16x8 al = *(const f16x8*)(AL + (size_t)ar * 128 + ks + quad * 8);
    #pragma unroll
    for (int nt = 0; nt < 4; ++nt) {
      int n = wc * 64 + nt * 16 + lm;
      f16x8 bh = *(const f16x8*)(W + (size_t)n * 136 + ks + quad * 8);
      f16x8 bl = *(const f16x8*)(W + (size_t)(128 + n) * 136 + ks + quad * 8);
      acc[nt] = __builtin_amdgcn_mfma_f32_16x16x32_f16(ah, bh, acc[nt], 0, 0, 0);
      acc[nt] = __builtin_amdgcn_mfma_f32_16x16x32_f16(ah, bl, acc[nt], 0, 0, 0);
      acc[nt] = __builtin_amdgcn_mfma_f32_16x16x32_f16(al, bh, acc[nt], 0, 0, 0);
    }
  }
  _Float16* Y = f.gY[g];
  #pragma unroll
  for (int i = 0; i < 4; ++i) {
    int grow = blockRow + wr * 16 + quad * 4 + i;
    if (grow >= M) continue;
    #pragma unroll
    for (int nt = 0; nt < 4; ++nt)
      Y[(size_t)grow * 128 + wc * 64 + nt * 16 + lm] = (_Float16)acc[nt][i];
  }
}

// ---------------- visit agg: single merged weighted loop (R12 body) --------
__global__ __launch_bounds__(256) void agg_visit(const int* __restrict__ mprefix,
                                                 const int2* __restrict__ mesrc,
                                                 const _Float16* __restrict__ YH,
                                                 _Float16* __restrict__ xvH,
                                                 _Float16* __restrict__ xvL, int doRelu) {
  int row = blockIdx.x * 16 + (threadIdx.x >> 4);
  if (row >= NVISIT) return;
  int q = threadIdx.x & 15;
  size_t o = (size_t)row * 128 + q * 8;
  f16x8 h0 = *(f16x8*)(xvH + o);
  f16x8 l0 = *(f16x8*)(xvL + o);
  float a[8];
  #pragma unroll
  for (int j = 0; j < 8; ++j) a[j] = (float)h0[j] + (float)l0[j];
  int e0 = mprefix[row], e1 = mprefix[row + 1];
  int e = e0;
  for (; e + 4 <= e1; e += 4) {
    int2 p0 = mesrc[e], p1 = mesrc[e + 1], p2 = mesrc[e + 2], p3 = mesrc[e + 3];
    f16x8 v0 = *(const f16x8*)(YH + (size_t)p0.x * 128 + q * 8);
    f16x8 v1 = *(const f16x8*)(YH + (size_t)p1.x * 128 + q * 8);
    f16x8 v2 = *(const f16x8*)(YH + (size_t)p2.x * 128 + q * 8);
    f16x8 v3 = *(const f16x8*)(YH + (size_t)p3.x * 128 + q * 8);
    float w0 = __int_as_float(p0.y), w1 = __int_as_float(p1.y);
    float w2 = __int_as_float(p2.y), w3 = __int_as_float(p3.y);
    #pragma unroll
    for (int j = 0; j < 8; ++j)
      a[j] += (w0 * (float)v0[j] + w1 * (float)v1[j]) +
              (w2 * (float)v2[j] + w3 * (float)v3[j]);
  }
  for (; e < e1; ++e) {
    int2 p = mesrc[e];
    f16x8 v = *(const f16x8*)(YH + (size_t)p.x * 128 + q * 8);
    float w = __int_as_float(p.y);
    #pragma unroll
    for (int j = 0; j < 8; ++j) a[j] += w * (float)v[j];
  }
  f16x8 h, l;
  #pragma unroll
  for (int j = 0; j < 8; ++j) {
    float v = doRelu ? fmaxf(a[j], 0.f) : a[j];
    h[j] = (_Float16)v;
    l[j] = (_Float16)(v - (float)h[j]);
  }
  *(f16x8*)(xvH + o) = h;
  *(f16x8*)(xvL + o) = l;
}

// ---------------- MFMA f16x3 GEMM, multi-task, split-plane A ---------------
__global__ __launch_bounds__(256, 2) void mgemm(MMeta mm) {
  int b = blockIdx.x;
  int ti = 0;
  for (int i = 1; i < mm.nTasks; ++i) if (b >= mm.t[i].blkOff) ti = i;
  MTask tk = mm.t[ti];
  int blockRow = (b - tk.blkOff) * 128;
  int Kpad = tk.K + 8;

  __shared__ _Float16 Ash[2][128][72];
  int tid = threadIdx.x;
  int wave = tid >> 6, lane = tid & 63;
  int quad = lane >> 4, lm = lane & 15;
  int wr = wave >> 1, wc = wave & 1;

  f32x4 acc[4][4];
  #pragma unroll
  for (int i = 0; i < 4; ++i)
    #pragma unroll
    for (int j = 0; j < 4; ++j) acc[i][j] = (f32x4){0.f, 0.f, 0.f, 0.f};

  const _Float16* wrowH[4];
  const _Float16* wrowL[4];
  #pragma unroll
  for (int nt = 0; nt < 4; ++nt) {
    int n = wc * 64 + nt * 16 + lm;
    wrowH[nt] = tk.W + (size_t)n * Kpad;
    wrowL[nt] = tk.W + (size_t)(128 + n) * Kpad;
  }

  int sr = tid >> 1, sk = (tid & 1) * 32;
  int gr = blockRow + sr; if (gr >= tk.M) gr = tk.M - 1;  // clamp (dup row ok)
  for (int k0 = 0; k0 < tk.K; k0 += 64) {
    const _Float16* AH = (k0 < 128) ? tk.AH0 : tk.AH1;
    const _Float16* AL = (k0 < 128) ? tk.AL0 : tk.AL1;
    size_t abase = (size_t)gr * 128 + (k0 & 127) + sk;
    #pragma unroll
    for (int c = 0; c < 4; ++c) {
      *(f16x8*)&Ash[0][sr][sk + c * 8] = *(const f16x8*)(AH + abase + c * 8);
      *(f16x8*)&Ash[1][sr][sk + c * 8] = *(const f16x8*)(AL + abase + c * 8);
    }
    __syncthreads();
    #pragma unroll
    for (int ks = 0; ks < 64; ks += 32) {
      int kf = k0 + ks + quad * 8;
      f16x8 bh[4], bl[4];
      #pragma unroll
      for (int nt = 0; nt < 4; ++nt) {
        bh[nt] = *(const f16x8*)(wrowH[nt] + kf);
        bl[nt] = *(const f16x8*)(wrowL[nt] + kf);
      }
      #pragma unroll
      for (int mt = 0; mt < 4; ++mt) {
        int r = wr * 64 + mt * 16 + lm;
        f16x8 ah = *(const f16x8*)&Ash[0][r][ks + quad * 8];
        f16x8 al = *(const f16x8*)&Ash[1][r][ks + quad * 8];
        #pragma unroll
        for (int nt = 0; nt < 4; ++nt) {
          acc[mt][nt] = __builtin_amdgcn_mfma_f32_16x16x32_f16(ah, bh[nt], acc[mt][nt], 0, 0, 0);
          acc[mt][nt] = __builtin_amdgcn_mfma_f32_16x16x32_f16(ah, bl[nt], acc[mt][nt], 0, 0, 0);
          acc[mt][nt] = __builtin_amdgcn_mfma_f32_16x16x32_f16(al, bh[nt], acc[mt][nt], 0, 0, 0);
        }
      }
    }
    __syncthreads();
  }

  float bv[4];
  #pragma unroll
  for (int nt = 0; nt < 4; ++nt)
    bv[nt] = tk.bias ? tk.bias[wc * 64 + nt * 16 + lm] : 0.f;
  #pragma unroll
  for (int mt = 0; mt < 4; ++mt) {
    #pragma unroll
    for (int i = 0; i < 4; ++i) {
      int grow = blockRow + wr * 64 + mt * 16 + quad * 4 + i;
      if (grow >= tk.M) continue;
      size_t ob = (size_t)grow * 128 + wc * 64 + lm;
      #pragma unroll
      for (int nt = 0; nt < 4; ++nt) {
        float v = acc[mt][nt][i] + bv[nt];
        if (tk.relu) v = fmaxf(v, 0.f);
        _Float16 h = (_Float16)v;
        tk.outH[ob + nt * 16] = h;
        if (tk.outL) tk.outL[ob + nt * 16] = (_Float16)(v - (float)h);
      }
    }
  }
}

// ---------------- factored classifier edge pass ----------------------------
__global__ __launch_bounds__(256) void cls_edge(
    const _Float16* __restrict__ UH, const _Float16* __restrict__ UL,
    const _Float16* __restrict__ VH, const _Float16* __restrict__ VL,
    const int* __restrict__ eli, const float* __restrict__ w2,
    const float* __restrict__ b2, const float* __restrict__ y,
    float* __restrict__ lossOut, float* __restrict__ pred, int M) {
  __shared__ float lsum[4];
  int tid = threadIdx.x;
  int q = tid & 15;
  int lane = tid & 63;
  float w2v[8];
  #pragma unroll
  for (int j = 0; j < 8; ++j) w2v[j] = w2[q * 8 + j];
  float bias = b2[0];
  float lacc = 0.f;
  int e0 = blockIdx.x * 128 + (tid >> 4);
  #pragma unroll
  for (int p = 0; p < 8; ++p) {
    int e = e0 + p * 16;
    if (e < M) {
      int vi = eli[e], di = eli[M + e];
      size_t uo = (size_t)vi * 128 + q * 8;
      size_t vo = (size_t)di * 128 + q * 8;
      f16x8 uh = *(const f16x8*)(UH + uo);
      f16x8 ul = *(const f16x8*)(UL + uo);
      f16x8 vh = *(const f16x8*)(VH + vo);
      f16x8 vl = *(const f16x8*)(VL + vo);
      float part = 0.f;
      #pragma unroll
      for (int j = 0; j < 8; ++j) {
        float t = ((float)uh[j] + (float)ul[j]) + ((float)vh[j] + (float)vl[j]);
        part += fmaxf(t, 0.f) * w2v[j];
      }
      part += __shfl_xor(part, 1);
      part += __shfl_xor(part, 2);
      part += __shfl_xor(part, 4);
      part += __shfl_xor(part, 8);
      if (q == 0) {
        float z = part + bias;
        pred[e] = z;
        lacc += fmaxf(z, 0.f) + log1pf(expf(-fabsf(z))) - z * y[e];
      }
    }
  }
  lacc += __shfl_xor(lacc, 16);
  lacc += __shfl_xor(lacc, 32);
  if (lane == 0) lsum[tid >> 6] = lacc;
  __syncthreads();
  if (tid == 0)
    atomicAdd(lossOut, (lsum[0] + lsum[1] + lsum[2] + lsum[3]) * (1.0f / 200000.0f));
}

// ---------------------------------------------------------------------------
extern "C" void kernel_launch(void* const* d_in, const int* in_sizes, int n_in,
                              void* d_out, int out_size, void* d_ws, size_t ws_size,
                              hipStream_t stream) {
  static const int kRows[6] = {20000, 100000, 4000, 8000, 10000, 4000};
  static const int kOff[6]  = {0, 20000, 120000, 124000, 132000, 142000};
  static const int kSmallT[5]   = {0, 2, 3, 4, 5};
  static const int kInRel[5]    = {1, 2, 4, 6, 8};
  static const int kCbcIn[5]    = {100000, 120000, 224000, 332000, 442000};
  static const int kYOff[5]     = {0, 20000, 24000, 32000, 42000};
  static const int kBOff[5]     = {0, 157, 189, 252, 331};
  static const int kAggOff[5]   = {0, 1250, 1500, 2000, 2625};   // 16-row blocks
  static const int kLeanOff[5]  = {0, 625, 750, 1000, 1313};     // 32-row blocks
  const int kAggTotal = 2875, kLeanTotal = 1438;
  // bucket config (rel order: pv,vp,vs,sv,vpr,prv,vd,dv,vdr,drv)
  static const int kCbcA[NREL]  = {0, 100000, 120000, 124000, 224000,
                                   232000, 332000, 342000, 442000, 446000};
  static const int kEhA[NREL]   = {100000, 100000, 300000, 300000, 200000,
                                   200000, 250000, 250000, 300000, 300000};
  static const int kNdst[NREL]  = {100000, 20000, 4000, 100000, 8000,
                                   100000, 10000, 100000, 4000, 100000};
  static const int kSh[NREL]    = {11, 9, 5, 10, 7, 10, 7, 10, 5, 10};
  static const int kNB[NREL]    = {49, 40, 125, 98, 63, 98, 79, 98, 125, 98};
  static const int kBB[NREL]    = {0, 49, 89, 214, 312, 375, 473, 552, 650, 775};

  const float* W_l = (const float*)d_in[22];
  const float* b_l = (const float*)d_in[23];
  const float* W_r = (const float*)d_in[24];
  const float* cw1 = (const float*)d_in[25];
  const float* cb1 = (const float*)d_in[26];
  const float* cw2 = (const float*)d_in[27];
  const float* cb2 = (const float*)d_in[28];
  const int* eli = (const int*)d_in[29];
  const float* ylab = (const float*)d_in[30];

  // workspace layout
  _Float16* H = (_Float16*)d_ws;                 // XELEMS
  _Float16* L = H + XELEMS;                      // XELEMS
  _Float16* meanH = L + XELEMS;                  // SELEMS
  _Float16* meanL = meanH + SELEMS;              // SELEMS
  _Float16* YH = meanL + SELEMS;                 // SELEMS
  _Float16* Wt = YH + SELEMS;                    // WT_ELEMS
  int* prefix = (int*)(Wt + WT_ELEMS);           // 546,004
  int* counts = prefix + 546004;                 // 546,000 (reused as mprefix)
  int* esrc = counts + NCOUNTS;                  // 2,300,000
  int* partials = esrc + NEDGES;                 // 1,024
  float* visitSumB = (float*)(partials + 1024);  // 512
  int* bcur = (int*)(visitSumB + 512);           // NBKT (+pad)
  int* bdata = bcur + 1024;                      // NBKT * BCAP ints (reused as mesrc)

  int* mprefix = counts;        // free after scan3
  int2* mesrc = (int2*)bdata;   // free after bkt_p2b

  // classifier U/V tables (alive only after layer-3; reuse dead regions)
  _Float16* UH = meanH;
  _Float16* VH = meanH + (size_t)NVISIT * 128;
  _Float16* VL = VH + (size_t)4000 * 128;
  _Float16* UL = (_Float16*)prefix;

  BkMeta bm;
  for (int r = 0; r < NREL; ++r) {
    bm.ei[r] = (const int*)d_in[12 + r];
    bm.E[r] = kEhA[r];
    bm.cbc[r] = kCbcA[r];
    bm.ndst[r] = kNdst[r];
    bm.sh[r] = kSh[r];
    bm.bb[r] = kBB[r];
    bm.nb[r] = kNB[r];
  }

  hipMemsetAsync(bcur, 0, NBKT * sizeof(int), stream);
  hipMemsetAsync(d_out, 0, sizeof(float), stream);

  // fused preamble: conv0 || prep_split || bkt_p1
  PreMeta pm;
  for (int t = 0; t < 6; ++t) {
    pm.nid[t] = (const int*)d_in[2 * t];
    pm.emb[t] = (const float*)d_in[2 * t + 1];
    pm.rows[t] = kRows[t];
    pm.off[t] = kOff[t];
  }
  pm.W_l = W_l; pm.b_l = b_l; pm.W_r = W_r; pm.cw1 = cw1;
  pm.Wt = Wt; pm.visitSumB = visitSumB;
  pre_all<<<dim3(42466), 256, 0, stream>>>(pm, bm, H, L, bcur, bdata);

  // CSR build (rest)
  bkt_p2a<<<dim3(NBKT), 256, 0, stream>>>(bm, bcur, bdata, counts);
  scan1<<<534, 1024, 0, stream>>>(counts, partials);
  scan2<<<1, 1024, 0, stream>>>(partials, 534);
  scan3<<<534, 1024, 0, stream>>>(counts, prefix, partials);
  bkt_p2b<<<dim3(NBKT), 256, 0, stream>>>(bm, bcur, bdata, prefix, esrc);
  merge_visit<<<dim3((NVISIT + 255) / 256), 256, 0, stream>>>(prefix, esrc, mprefix, mesrc);

  _Float16* xvH = H + (size_t)kOff[1] * 128;
  _Float16* xvL = L + (size_t)kOff[1] * 128;

  for (int l = 0; l < 4; ++l) {
    int doRelu = (l < 3);
    int last = (l == 3);
    _Float16* LW = Wt + (size_t)l * PLW;

    // F1: agg_small (first) || lean Y_q
    F1Meta f1;
    if (!last) {
      for (int t = 0; t < 5; ++t) {
        f1.rp[t] = prefix + kCbcIn[t];
        f1.mH[t] = meanH + (size_t)kYOff[t] * 128;
        f1.mL[t] = meanL + (size_t)kYOff[t] * 128;
        f1.aM[t] = kRows[kSmallT[t]];
        f1.aOff[t] = kAggOff[t];
      }
      f1.nAgg = 5;
      f1.aggTotal = kAggTotal;
    } else {
      f1.rp[0] = prefix + kCbcIn[4];
      f1.mH[0] = meanH + (size_t)kYOff[4] * 128;
      f1.mL[0] = meanL + (size_t)kYOff[4] * 128;
      f1.aM[0] = 4000;
      f1.aOff[0] = 0;
      for (int t = 1; t < 5; ++t) { f1.rp[t] = nullptr; f1.mH[t] = nullptr; f1.mL[t] = nullptr; f1.aM[t] = 0; f1.aOff[t] = 0; }
      f1.nAgg = 1;
      f1.aggTotal = 250;
    }
    for (int q = 0; q < 5; ++q) {
      size_t so = (size_t)kOff[kSmallT[q]] * 128;
      f1.gAH[q] = H + so;
      f1.gAL[q] = L + so;
      f1.gW[q] = LW + 337920 + (size_t)q * 34816;
      f1.gY[q] = YH + (size_t)kYOff[q] * 128;
      f1.gM[q] = kRows[kSmallT[q]];
      f1.gOff[q] = kLeanOff[q];
    }
    f1.nG = 5;
    fused1<<<dim3(f1.aggTotal + kLeanTotal), 256, 0, stream>>>(f1, xvH, esrc);

    // F2: m1 (small-dst [mean|x_old]@[Wl;Wr]) || m2_visit (in-place), one grid
    MMeta m;
    if (!last) {
      m.nTasks = 6;
      for (int t = 0; t < 5; ++t) {
        size_t mo = (size_t)kYOff[t] * 128;
        size_t so = (size_t)kOff[kSmallT[t]] * 128;
        m.t[t].AH0 = meanH + mo; m.t[t].AL0 = meanL + mo;
        m.t[t].AH1 = H + so;     m.t[t].AL1 = L + so;
        m.t[t].W = LW + (size_t)t * 67584;
        m.t[t].bias = b_l + (size_t)(l * 10 + kInRel[t]) * 128;
        m.t[t].outH = H + so;    m.t[t].outL = L + so;
        m.t[t].M = kRows[kSmallT[t]];
        m.t[t].blkOff = kBOff[t];
        m.t[t].K = 256;
        m.t[t].relu = doRelu;
      }
      m.t[5].AH0 = xvH; m.t[5].AL0 = xvL;
      m.t[5].AH1 = nullptr; m.t[5].AL1 = nullptr;
      m.t[5].W = LW + 512000;
      m.t[5].bias = visitSumB + l * 128;
      m.t[5].outH = xvH; m.t[5].outL = xvL;   // in-place (block-local rows)
      m.t[5].M = NVISIT;
      m.t[5].blkOff = 363;
      m.t[5].K = 128;
      m.t[5].relu = 0;
      mgemm<<<dim3(363 + 782), 256, 0, stream>>>(m);
    } else {
      size_t mo = (size_t)kYOff[4] * 128;
      size_t so = (size_t)kOff[5] * 128;   // drug
      m.nTasks = 2;
      m.t[0].AH0 = meanH + mo; m.t[0].AL0 = meanL + mo;
      m.t[0].AH1 = H + so;     m.t[0].AL1 = L + so;
      m.t[0].W = LW + (size_t)4 * 67584;
      m.t[0].bias = b_l + (size_t)(l * 10 + kInRel[4]) * 128;
      m.t[0].outH = H + so;    m.t[0].outL = L + so;
      m.t[0].M = 4000;
      m.t[0].blkOff = 0;
      m.t[0].K = 256;
      m.t[0].relu = 0;
      m.t[1].AH0 = xvH; m.t[1].AL0 = xvL;
      m.t[1].AH1 = nullptr; m.t[1].AL1 = nullptr;
      m.t[1].W = LW + 512000;
      m.t[1].bias = visitSumB + l * 128;
      m.t[1].outH = xvH; m.t[1].outL = xvL;
      m.t[1].M = NVISIT;
      m.t[1].blkOff = 32;
      m.t[1].K = 128;
      m.t[1].relu = 0;
      mgemm<<<dim3(32 + 782), 256, 0, stream>>>(m);
    }

    // F3: x_v(H,L) += weighted merged gather of YH; relu; re-split
    agg_visit<<<dim3(6250), 256, 0, stream>>>(mprefix, mesrc, YH, xvH, xvL, doRelu);
  }

  // classifier precompute: U = xv@W1top + b1 (split), V = xd@W1bot (split)
  MMeta muv;
  muv.nTasks = 2;
  muv.t[0].AH0 = xvH; muv.t[0].AL0 = xvL;
  muv.t[0].AH1 = nullptr; muv.t[0].AL1 = nullptr;
  muv.t[0].W = Wt + (size_t)4 * PLW;
  muv.t[0].bias = cb1;
  muv.t[0].outH = UH; muv.t[0].outL = UL;
  muv.t[0].M = NVISIT;
  muv.t[0].blkOff = 0;
  muv.t[0].K = 128;
  muv.t[0].relu = 0;
  muv.t[1].AH0 = H + (size_t)kOff[5] * 128; muv.t[1].AL0 = L + (size_t)kOff[5] * 128;
  muv.t[1].AH1 = nullptr; muv.t[1].AL1 = nullptr;
  muv.t[1].W = Wt + (size_t)4 * PLW + 34816;
  muv.t[1].bias = nullptr;
  muv.t[1].outH = VH; muv.t[1].outL = VL;
  muv.t[1].M = 4000;
  muv.t[1].blkOff = 782;
  muv.t[1].K = 128;
  muv.t[1].relu = 0;
  mgemm<<<dim3(782 + 32), 256, 0, stream>>>(muv);

  const int ML = 200000;
  cls_edge<<<dim3((ML + 127) / 128), 256, 0, stream>>>(
      UH, UL, VH, VL, eli, cw2, cb2, ylab,
      (float*)d_out, (float*)d_out + 1, ML);
}

// Round 11
// 904.215 us; speedup vs baseline: 1.0917x; 1.0054x over previous
//
#include <hip/hip_runtime.h>
#include <cmath>

// ---------------------------------------------------------------------------
// Hetero-SAGE GNN (4 layers, 10 relations, D=128) + edge classifier.
// R20: preamble spread as filler through the CSR chain. R19's pre_all (90us,
//   1.9TB/s, occ 37%) was the #1 dispatch while the CSR chain (~55us) ran
//   tiny underutilized launches. conv0 (flattened: 9125 blocks, was 37500
//   with 28k empty) + prep are independent of the CSR chain, so:
//   K1{p1+prep} -> K2{p2a+conv/3000} -> scan1/2/3 -> K3{p2b+conv/1500,
//   small chunk: p2b's 53KB LDS caps residency} -> K4{merge+conv/4625}.
//   CSR blocks FIRST per launch (they gate the next launch; LPT on the
//   critical path). All math bodies bit-identical.
// R19: agg-first fused1 (LPT within launch). R16: fused1 (agg_small||leanYq),
//   F2=mgemm{m1 x5, visit}, F3=agg_visit. R11: factored classifier.
// R10: merged weighted visit-CSR. R9: bucket-sort CSR build. R8: split-f16
//   H/L planes, f16x3 MFMA GEMMs, layer-3 pruning.
// ---------------------------------------------------------------------------

typedef _Float16 f16x8 __attribute__((ext_vector_type(8)));
typedef float f32x4 __attribute__((ext_vector_type(4)));

#define NREL 10
#define NCOUNTS 546000
#define NEDGES  2300000
#define NVISIT  100000
#define NVEDGES 1150000
#define PLW 546816
#define WT_ELEMS (4 * PLW + 69632)
#define XELEMS 18688000UL   // 146000*128
#define SELEMS 5888000UL    // 46000*128
#define NBKT 873
#define BCAP 5056
#define NMERGE 391          // (NVISIT+255)/256
#define CONV_BLKS 9125      // 146000*16/256 exactly

struct BkMeta {
  const int* ei[NREL]; int E[NREL]; int cbc[NREL]; int ndst[NREL];
  int sh[NREL]; int bb[NREL]; int nb[NREL];
};
struct PreMeta {
  const float* emb[6]; const int* nid[6]; int off[6];
  const float* W_l; const float* b_l; const float* W_r; const float* cw1;
  _Float16* Wt; float* visitSumB;
};
struct MTask {
  const _Float16* AH0; const _Float16* AL0;  // k in [0,128)
  const _Float16* AH1; const _Float16* AL1;  // k in [128,256)
  const _Float16* W;                         // [2][128][Kpad] h then l plane
  const float* bias;                         // nullable
  _Float16* outH; _Float16* outL;            // outL nullable (h-only output)
  int M, blkOff, K, relu;
};
struct MMeta { MTask t[6]; int nTasks; };
// F1: agg_small blocks first (LPT), then lean Y_q gemm blocks
struct F1Meta {
  const int* rp[5]; _Float16* mH[5]; _Float16* mL[5]; int aM[5]; int aOff[5];
  int nAgg; int aggTotal;
  const _Float16* gAH[5]; const _Float16* gAL[5]; const _Float16* gW[5];
  _Float16* gY[5]; int gM[5]; int gOff[5]; int nG;
};

// ---------------- conv0 body (flattened over 146000 concatenated rows) -----
__device__ __forceinline__ void conv0_body(const PreMeta& pm, int bc, int tid,
                                           _Float16* __restrict__ H,
                                           _Float16* __restrict__ L) {
  int i = bc * 256 + tid;
  if (i >= 146000 * 16) return;
  int g = i >> 4, q = i & 15;
  int t = 0;
  #pragma unroll
  for (int k = 1; k < 6; ++k) if (g >= pm.off[k]) t = k;
  int row = g - pm.off[t];
  int s = pm.nid[t][row];
  const float* p = pm.emb[t] + (size_t)s * 128 + q * 8;
  float4 v0 = *(const float4*)p;
  float4 v1 = *(const float4*)(p + 4);
  float v[8] = {v0.x, v0.y, v0.z, v0.w, v1.x, v1.y, v1.z, v1.w};
  f16x8 h, l;
  #pragma unroll
  for (int j = 0; j < 8; ++j) {
    h[j] = (_Float16)v[j];
    l[j] = (_Float16)(v[j] - (float)h[j]);
  }
  size_t o = (size_t)g * 128 + q * 8;
  *(f16x8*)(H + o) = h;
  *(f16x8*)(L + o) = l;
}

// ---------------- prep body -------------------------------------------------
__device__ __forceinline__ void prep_body(const PreMeta& pm, int gid) {
  const int visitRel[5] = {0, 3, 5, 7, 9};
  const int inRel[5] = {1, 2, 4, 6, 8};
  if (gid < 1048576) {
    int l = gid >> 18, o = gid & 262143;
    float val; size_t wbase; int n, k, Kpad;
    if (o < 163840) {          // small stacks, K=256
      int t = o >> 15, e = o & 32767;
      k = e >> 7; n = e & 127; Kpad = 264;
      int r = inRel[t];
      val = (k < 128) ? pm.W_l[(size_t)(l * 10 + r) * 16384 + k * 128 + n]
                      : pm.W_r[(size_t)(l * 10 + r) * 16384 + (k - 128) * 128 + n];
      wbase = (size_t)l * PLW + t * 67584;
    } else if (o < 245760) {   // trans Wl, K=128
      int q = (o - 163840) >> 14, e = (o - 163840) & 16383;
      k = e >> 7; n = e & 127; Kpad = 136;
      val = pm.W_l[(size_t)(l * 10 + visitRel[q]) * 16384 + k * 128 + n];
      wbase = (size_t)l * PLW + 337920 + q * 34816;
    } else {                   // SumWr, K=128
      int e = o - 245760;
      k = e >> 7; n = e & 127; Kpad = 136;
      val = 0.f;
      #pragma unroll
      for (int q = 0; q < 5; ++q)
        val += pm.W_r[(size_t)(l * 10 + visitRel[q]) * 16384 + k * 128 + n];
      wbase = (size_t)l * PLW + 512000;
    }
    _Float16 h = (_Float16)val;
    _Float16 lo = (_Float16)(val - (float)h);
    pm.Wt[wbase + (size_t)n * Kpad + k] = h;
    pm.Wt[wbase + (size_t)(128 + n) * Kpad + k] = lo;
  } else if (gid < 1081344) {  // cls W1 -> two K=128 split layouts (top|bot)
    int e = gid - 1048576;
    int k = e >> 7, n = e & 127;
    float val = pm.cw1[(size_t)k * 128 + n];
    _Float16 h = (_Float16)val;
    _Float16 lo = (_Float16)(val - (float)h);
    size_t wbase = (size_t)4 * PLW + (k < 128 ? 0 : 34816);
    int kk = k & 127;
    pm.Wt[wbase + (size_t)n * 136 + kk] = h;
    pm.Wt[wbase + (size_t)(128 + n) * 136 + kk] = lo;
  } else if (gid < 1081856) {  // visit summed bias
    int e = gid - 1081344;
    int l = e >> 7, c = e & 127;
    float val = 0.f;
    #pragma unroll
    for (int q = 0; q < 5; ++q) val += pm.b_l[(l * 10 + visitRel[q]) * 128 + c];
    pm.visitSumB[e] = val;
  }
}

// ---------------- K1: bkt_p1 (740, first) + prep (4226) --------------------
__global__ __launch_bounds__(256) void k1_p1_prep(BkMeta bm, PreMeta pm,
                                                  int* __restrict__ bcur,
                                                  int* __restrict__ bdata) {
  __shared__ int cnt[128];
  __shared__ int base[128];
  __shared__ unsigned short rnk[4096];
  int b = blockIdx.x;
  int tid = threadIdx.x;
  if (b >= 740) {
    prep_body(pm, (b - 740) * 256 + tid);
    return;
  }
  int r = b / 74;
  int bx = b - r * 74;
  int E = bm.E[r], sh = bm.sh[r], bb = bm.bb[r], nb = bm.nb[r];
  if (tid < 128) cnt[tid] = 0;
  __syncthreads();
  int e0 = bx * 4096;
  if (e0 >= E) return;
  const int* dstp = bm.ei[r] + E;
  const int* srcp = bm.ei[r];
  #pragma unroll
  for (int i = 0; i < 16; ++i) {
    int e = e0 + i * 256 + tid;
    if (e < E) {
      int bk = dstp[e] >> sh;
      rnk[i * 256 + tid] = (unsigned short)atomicAdd(&cnt[bk], 1);
    }
  }
  __syncthreads();
  if (tid < nb && cnt[tid] > 0) base[tid] = atomicAdd(&bcur[bb + tid], cnt[tid]);
  __syncthreads();
  #pragma unroll
  for (int i = 0; i < 16; ++i) {
    int e = e0 + i * 256 + tid;
    if (e < E) {
      int d = dstp[e];
      int bk = d >> sh;
      int pos = base[bk] + (int)rnk[i * 256 + tid];
      if (pos < BCAP)
        bdata[(size_t)(bb + bk) * BCAP + pos] = ((d & ((1 << sh) - 1)) << 17) | srcp[e];
    }
  }
}

// ---------------- K2: p2a (873, first) + conv chunk -------------------------
__global__ __launch_bounds__(256) void k2_p2a_conv(BkMeta bm, PreMeta pm,
                                                   const int* __restrict__ bcur,
                                                   const int* __restrict__ bdata,
                                                   int* __restrict__ counts,
                                                   _Float16* __restrict__ H,
                                                   _Float16* __restrict__ L,
                                                   int convBase) {
  __shared__ int hist[2048];
  int b = blockIdx.x;
  int tid = threadIdx.x;
  if (b >= NBKT) {
    conv0_body(pm, convBase + b - NBKT, tid, H, L);
    return;
  }
  int g = b;
  int r = 0;
  #pragma unroll
  for (int i = 1; i < NREL; ++i) if (g >= bm.bb[i]) r = i;
  int lb = g - bm.bb[r];
  int sh = bm.sh[r], dpb = 1 << sh;
  for (int d = tid; d < dpb; d += 256) hist[d] = 0;
  __syncthreads();
  int cnt = bcur[g]; if (cnt > BCAP) cnt = BCAP;
  const int* bd = bdata + (size_t)g * BCAP;
  for (int i = tid; i < cnt; i += 256) atomicAdd(&hist[((unsigned)bd[i]) >> 17], 1);
  __syncthreads();
  int dBase = lb << sh;
  int dMax = bm.ndst[r] - dBase; if (dMax > dpb) dMax = dpb;
  for (int d = tid; d < dMax; d += 256) counts[bm.cbc[r] + dBase + d] = hist[d];
}

// ---------------- global scan (3-phase, unchanged) --------------------------
__global__ __launch_bounds__(1024) void scan1(const int* __restrict__ counts,
                                              int* __restrict__ partials) {
  __shared__ int s[1024];
  int i = blockIdx.x * 1024 + threadIdx.x;
  s[threadIdx.x] = (i < NCOUNTS) ? counts[i] : 0;
  __syncthreads();
  for (int off = 512; off > 0; off >>= 1) {
    if (threadIdx.x < off) s[threadIdx.x] += s[threadIdx.x + off];
    __syncthreads();
  }
  if (threadIdx.x == 0) partials[blockIdx.x] = s[0];
}

__global__ __launch_bounds__(1024) void scan2(int* __restrict__ partials, int nb) {
  __shared__ int s[1024];
  int t = threadIdx.x;
  int v = (t < nb) ? partials[t] : 0;
  s[t] = v;
  __syncthreads();
  for (int off = 1; off < 1024; off <<= 1) {
    int add = (t >= off) ? s[t - off] : 0;
    __syncthreads();
    s[t] += add;
    __syncthreads();
  }
  if (t < nb) partials[t] = s[t] - v;  // exclusive
}

__global__ __launch_bounds__(1024) void scan3(const int* __restrict__ counts,
                                              int* __restrict__ prefix,
                                              const int* __restrict__ partials) {
  __shared__ int s[1024];
  int t = threadIdx.x;
  int i = blockIdx.x * 1024 + t;
  int v = (i < NCOUNTS) ? counts[i] : 0;
  s[t] = v;
  __syncthreads();
  for (int off = 1; off < 1024; off <<= 1) {
    int add = (t >= off) ? s[t - off] : 0;
    __syncthreads();
    s[t] += add;
    __syncthreads();
  }
  int P = partials[blockIdx.x] + s[t] - v;
  if (i < NCOUNTS) prefix[i] = P;
  if (blockIdx.x == 0 && t == 0) prefix[NCOUNTS] = NEDGES;
}

// ---------------- K3: p2b (873, first) + conv chunk -------------------------
__global__ __launch_bounds__(256) void k3_p2b_conv(BkMeta bm, PreMeta pm,
                                                   const int* __restrict__ bcur,
                                                   const int* __restrict__ bdata,
                                                   const int* __restrict__ prefix,
                                                   int* __restrict__ esrc,
                                                   _Float16* __restrict__ H,
                                                   _Float16* __restrict__ L,
                                                   int convBase) {
  __shared__ int pk[BCAP];
  __shared__ int srt[BCAP];
  __shared__ int cur[2048];
  __shared__ int part[256];
  __shared__ int baseSh;
  int b = blockIdx.x;
  int tid = threadIdx.x;
  if (b >= NBKT) {
    conv0_body(pm, convBase + b - NBKT, tid, H, L);
    return;
  }
  int g = b;
  int r = 0;
  #pragma unroll
  for (int i = 1; i < NREL; ++i) if (g >= bm.bb[i]) r = i;
  int lb = g - bm.bb[r];
  int sh = bm.sh[r], dpb = 1 << sh;
  int cnt = bcur[g]; if (cnt > BCAP) cnt = BCAP;
  const int* bd = bdata + (size_t)g * BCAP;
  for (int d = tid; d < dpb; d += 256) cur[d] = 0;
  for (int i = tid; i < cnt; i += 256) pk[i] = bd[i];
  __syncthreads();
  for (int i = tid; i < cnt; i += 256) atomicAdd(&cur[((unsigned)pk[i]) >> 17], 1);
  __syncthreads();
  int seg = (dpb + 255) >> 8;
  int s = 0;
  int b0 = tid * seg;
  for (int j = 0; j < seg; ++j) {
    int idx = b0 + j;
    if (idx < dpb) { int v = cur[idx]; cur[idx] = s; s += v; }
  }
  part[tid] = s;
  __syncthreads();
  for (int off = 1; off < 256; off <<= 1) {
    int add = (tid >= off) ? part[tid - off] : 0;
    __syncthreads();
    part[tid] += add;
    __syncthreads();
  }
  int myoff = part[tid] - s;
  for (int j = 0; j < seg; ++j) {
    int idx = b0 + j;
    if (idx < dpb) cur[idx] += myoff;
  }
  if (tid == 0) baseSh = prefix[bm.cbc[r] + (lb << sh)];
  __syncthreads();
  for (int i = tid; i < cnt; i += 256) {
    int p = pk[i];
    int pos = atomicAdd(&cur[((unsigned)p) >> 17], 1);
    srt[pos] = p & 0x1FFFF;
  }
  __syncthreads();
  int base = baseSh;
  for (int i = tid; i < cnt; i += 256) esrc[base + i] = srt[i];
}

// ---------------- K4: merge_visit (391, first) + conv chunk -----------------
__global__ __launch_bounds__(256) void k4_merge_conv(PreMeta pm,
                                                     const int* __restrict__ prefix,
                                                     const int* __restrict__ esrc,
                                                     int* __restrict__ mprefix,
                                                     int2* __restrict__ mesrc,
                                                     _Float16* __restrict__ H,
                                                     _Float16* __restrict__ L,
                                                     int convBase) {
  int b = blockIdx.x;
  int tid = threadIdx.x;
  if (b >= NMERGE) {
    conv0_body(pm, convBase + b - NMERGE, tid, H, L);
    return;
  }
  const int cbc[5]  = {0, 124000, 232000, 342000, 446000};
  const int yoff[5] = {0, 20000, 24000, 32000, 42000};
  int v = b * 256 + tid;
  if (v >= NVISIT) return;
  int e0[5], e1[5];
  int base = 0;
  #pragma unroll
  for (int q = 0; q < 5; ++q) {
    e0[q] = prefix[cbc[q] + v];
    e1[q] = prefix[cbc[q] + v + 1];
    base += e0[q] - prefix[cbc[q]];
  }
  mprefix[v] = base;
  if (v == NVISIT - 1) {
    int t = base;
    #pragma unroll
    for (int q = 0; q < 5; ++q) t += e1[q] - e0[q];
    mprefix[NVISIT] = t;
  }
  int pos = base;
  #pragma unroll
  for (int q = 0; q < 5; ++q) {
    int d = e1[q] - e0[q];
    if (d > 0) {
      int wb = __float_as_int(1.f / (float)d);
      for (int e = e0[q]; e < e1[q]; ++e)
        mesrc[pos++] = make_int2(yoff[q] + esrc[e], wb);
    }
  }
}

// ---------------- F1: agg_small (first, LPT) || lean no-LDS Y_q GEMM -------
__global__ __launch_bounds__(256, 8) void fused1(F1Meta f,
                                                 const _Float16* __restrict__ xvH,
                                                 const int* __restrict__ esrc) {
  int b = blockIdx.x;
  int tid = threadIdx.x;
  if (b < f.aggTotal) {
    int t = 0;
    #pragma unroll
    for (int i = 1; i < 5; ++i) if (i < f.nAgg && b >= f.aOff[i]) t = i;
    int row = (b - f.aOff[t]) * 16 + (tid >> 4);
    if (row >= f.aM[t]) return;
    int q = tid & 15;
    const int* rp = f.rp[t];
    int e0 = rp[row], e1 = rp[row + 1];
    float a[8];
    #pragma unroll
    for (int j = 0; j < 8; ++j) a[j] = 0.f;
    int e = e0;
    for (; e + 4 <= e1; e += 4) {
      int s0 = esrc[e], s1 = esrc[e + 1], s2 = esrc[e + 2], s3 = esrc[e + 3];
      f16x8 v0 = *(const f16x8*)(xvH + (size_t)s0 * 128 + q * 8);
      f16x8 v1 = *(const f16x8*)(xvH + (size_t)s1 * 128 + q * 8);
      f16x8 v2 = *(const f16x8*)(xvH + (size_t)s2 * 128 + q * 8);
      f16x8 v3 = *(const f16x8*)(xvH + (size_t)s3 * 128 + q * 8);
      #pragma unroll
      for (int j = 0; j < 8; ++j)
        a[j] += ((float)v0[j] + (float)v1[j]) + ((float)v2[j] + (float)v3[j]);
    }
    for (; e < e1; ++e) {
      int s = esrc[e];
      f16x8 v = *(const f16x8*)(xvH + (size_t)s * 128 + q * 8);
      #pragma unroll
      for (int j = 0; j < 8; ++j) a[j] += (float)v[j];
    }
    float inv = (e1 > e0) ? 1.f / (float)(e1 - e0) : 0.f;
    f16x8 h, l;
    #pragma unroll
    for (int j = 0; j < 8; ++j) {
      float v = a[j] * inv;
      h[j] = (_Float16)v;
      l[j] = (_Float16)(v - (float)h[j]);
    }
    size_t o = (size_t)row * 128 + q * 8;
    *(f16x8*)(f.mH[t] + o) = h;
    *(f16x8*)(f.mL[t] + o) = l;
    return;
  }
  // ---- lean Y_q gemm ----
  b -= f.aggTotal;
  int g = 0;
  #pragma unroll
  for (int i = 1; i < 5; ++i) if (i < f.nG && b >= f.gOff[i]) g = i;
  int blockRow = (b - f.gOff[g]) * 32;
  int lane = tid & 63, wave = tid >> 6;
  int quad = lane >> 4, lm = lane & 15;
  int wr = wave >> 1, wc = wave & 1;
  const _Float16* AH = f.gAH[g];
  const _Float16* AL = f.gAL[g];
  const _Float16* W = f.gW[g];
  int M = f.gM[g];
  int ar = blockRow + wr * 16 + lm;
  if (ar >= M) ar = M - 1;  // clamp (dup row ok)
  f32x4 acc[4];
  #pragma unroll
  for (int nt = 0; nt < 4; ++nt) acc[nt] = (f32x4){0.f, 0.f, 0.f, 0.f};
  for (int ks = 0; ks < 128; ks += 32) {
    f16x8 ah = *(const f16x8*)(AH + (size_t)ar * 128 + ks + quad * 8);
    f16x8 al = *(const f16x8*)(AL + (size_t)ar * 128 + ks + quad * 8);
    #pragma unroll
    for (int nt = 0; nt < 4; ++nt) {
      int n = wc * 64 + nt * 16 + lm;
      f16x8 bh = *(const f16x8*)(W + (size_t)n * 136 + ks + quad * 8);
      f16x8 bl = *(const f16x8*)(W + (size_t)(128 + n) * 136 + ks + quad * 8);
      acc[nt] = __builtin_amdgcn_mfma_f32_16x16x32_f16(ah, bh, acc[nt], 0, 0, 0);
      acc[nt] = __builtin_amdgcn_mfma_f32_16x16x32_f16(ah, bl, acc[nt], 0, 0, 0);
      acc[nt] = __builtin_amdgcn_mfma_f32_16x16x32_f16(al, bh, acc[nt], 0, 0, 0);
    }
  }
  _Float16* Y = f.gY[g];
  #pragma unroll
  for (int i = 0; i < 4; ++i) {
    int grow = blockRow + wr * 16 + quad * 4 + i;
    if (grow >= M) continue;
    #pragma unroll
    for (int nt = 0; nt < 4; ++nt)
      Y[(size_t)grow * 128 + wc * 64 + nt * 16 + lm] = (_Float16)acc[nt][i];
  }
}

// ---------------- visit agg: single merged weighted loop (R12 body) --------
__global__ __launch_bounds__(256) void agg_visit(const int* __restrict__ mprefix,
                                                 const int2* __restrict__ mesrc,
                                                 const _Float16* __restrict__ YH,
                                                 _Float16* __restrict__ xvH,
                                                 _Float16* __restrict__ xvL, int doRelu) {
  int row = blockIdx.x * 16 + (threadIdx.x >> 4);
  if (row >= NVISIT) return;
  int q = threadIdx.x & 15;
  size_t o = (size_t)row * 128 + q * 8;
  f16x8 h0 = *(f16x8*)(xvH + o);
  f16x8 l0 = *(f16x8*)(xvL + o);
  float a[8];
  #pragma unroll
  for (int j = 0; j < 8; ++j) a[j] = (float)h0[j] + (float)l0[j];
  int e0 = mprefix[row], e1 = mprefix[row + 1];
  int e = e0;
  for (; e + 4 <= e1; e += 4) {
    int2 p0 = mesrc[e], p1 = mesrc[e + 1], p2 = mesrc[e + 2], p3 = mesrc[e + 3];
    f16x8 v0 = *(const f16x8*)(YH + (size_t)p0.x * 128 + q * 8);
    f16x8 v1 = *(const f16x8*)(YH + (size_t)p1.x * 128 + q * 8);
    f16x8 v2 = *(const f16x8*)(YH + (size_t)p2.x * 128 + q * 8);
    f16x8 v3 = *(const f16x8*)(YH + (size_t)p3.x * 128 + q * 8);
    float w0 = __int_as_float(p0.y), w1 = __int_as_float(p1.y);
    float w2 = __int_as_float(p2.y), w3 = __int_as_float(p3.y);
    #pragma unroll
    for (int j = 0; j < 8; ++j)
      a[j] += (w0 * (float)v0[j] + w1 * (float)v1[j]) +
              (w2 * (float)v2[j] + w3 * (float)v3[j]);
  }
  for (; e < e1; ++e) {
    int2 p = mesrc[e];
    f16x8 v = *(const f16x8*)(YH + (size_t)p.x * 128 + q * 8);
    float w = __int_as_float(p.y);
    #pragma unroll
    for (int j = 0; j < 8; ++j) a[j] += w * (float)v[j];
  }
  f16x8 h, l;
  #pragma unroll
  for (int j = 0; j < 8; ++j) {
    float v = doRelu ? fmaxf(a[j], 0.f) : a[j];
    h[j] = (_Float16)v;
    l[j] = (_Float16)(v - (float)h[j]);
  }
  *(f16x8*)(xvH + o) = h;
  *(f16x8*)(xvL + o) = l;
}

// ---------------- MFMA f16x3 GEMM, multi-task, split-plane A ---------------
__global__ __launch_bounds__(256, 2) void mgemm(MMeta mm) {
  int b = blockIdx.x;
  int ti = 0;
  for (int i = 1; i < mm.nTasks; ++i) if (b >= mm.t[i].blkOff) ti = i;
  MTask tk = mm.t[ti];
  int blockRow = (b - tk.blkOff) * 128;
  int Kpad = tk.K + 8;

  __shared__ _Float16 Ash[2][128][72];
  int tid = threadIdx.x;
  int wave = tid >> 6, lane = tid & 63;
  int quad = lane >> 4, lm = lane & 15;
  int wr = wave >> 1, wc = wave & 1;

  f32x4 acc[4][4];
  #pragma unroll
  for (int i = 0; i < 4; ++i)
    #pragma unroll
    for (int j = 0; j < 4; ++j) acc[i][j] = (f32x4){0.f, 0.f, 0.f, 0.f};

  const _Float16* wrowH[4];
  const _Float16* wrowL[4];
  #pragma unroll
  for (int nt = 0; nt < 4; ++nt) {
    int n = wc * 64 + nt * 16 + lm;
    wrowH[nt] = tk.W + (size_t)n * Kpad;
    wrowL[nt] = tk.W + (size_t)(128 + n) * Kpad;
  }

  int sr = tid >> 1, sk = (tid & 1) * 32;
  int gr = blockRow + sr; if (gr >= tk.M) gr = tk.M - 1;  // clamp (dup row ok)
  for (int k0 = 0; k0 < tk.K; k0 += 64) {
    const _Float16* AH = (k0 < 128) ? tk.AH0 : tk.AH1;
    const _Float16* AL = (k0 < 128) ? tk.AL0 : tk.AL1;
    size_t abase = (size_t)gr * 128 + (k0 & 127) + sk;
    #pragma unroll
    for (int c = 0; c < 4; ++c) {
      *(f16x8*)&Ash[0][sr][sk + c * 8] = *(const f16x8*)(AH + abase + c * 8);
      *(f16x8*)&Ash[1][sr][sk + c * 8] = *(const f16x8*)(AL + abase + c * 8);
    }
    __syncthreads();
    #pragma unroll
    for (int ks = 0; ks < 64; ks += 32) {
      int kf = k0 + ks + quad * 8;
      f16x8 bh[4], bl[4];
      #pragma unroll
      for (int nt = 0; nt < 4; ++nt) {
        bh[nt] = *(const f16x8*)(wrowH[nt] + kf);
        bl[nt] = *(const f16x8*)(wrowL[nt] + kf);
      }
      #pragma unroll
      for (int mt = 0; mt < 4; ++mt) {
        int r = wr * 64 + mt * 16 + lm;
        f16x8 ah = *(const f16x8*)&Ash[0][r][ks + quad * 8];
        f16x8 al = *(const f16x8*)&Ash[1][r][ks + quad * 8];
        #pragma unroll
        for (int nt = 0; nt < 4; ++nt) {
          acc[mt][nt] = __builtin_amdgcn_mfma_f32_16x16x32_f16(ah, bh[nt], acc[mt][nt], 0, 0, 0);
          acc[mt][nt] = __builtin_amdgcn_mfma_f32_16x16x32_f16(ah, bl[nt], acc[mt][nt], 0, 0, 0);
          acc[mt][nt] = __builtin_amdgcn_mfma_f32_16x16x32_f16(al, bh[nt], acc[mt][nt], 0, 0, 0);
        }
      }
    }
    __syncthreads();
  }

  float bv[4];
  #pragma unroll
  for (int nt = 0; nt < 4; ++nt)
    bv[nt] = tk.bias ? tk.bias[wc * 64 + nt * 16 + lm] : 0.f;
  #pragma unroll
  for (int mt = 0; mt < 4; ++mt) {
    #pragma unroll
    for (int i = 0; i < 4; ++i) {
      int grow = blockRow + wr * 64 + mt * 16 + quad * 4 + i;
      if (grow >= tk.M) continue;
      size_t ob = (size_t)grow * 128 + wc * 64 + lm;
      #pragma unroll
      for (int nt = 0; nt < 4; ++nt) {
        float v = acc[mt][nt][i] + bv[nt];
        if (tk.relu) v = fmaxf(v, 0.f);
        _Float16 h = (_Float16)v;
        tk.outH[ob + nt * 16] = h;
        if (tk.outL) tk.outL[ob + nt * 16] = (_Float16)(v - (float)h);
      }
    }
  }
}

// ---------------- factored classifier edge pass ----------------------------
__global__ __launch_bounds__(256) void cls_edge(
    const _Float16* __restrict__ UH, const _Float16* __restrict__ UL,
    const _Float16* __restrict__ VH, const _Float16* __restrict__ VL,
    const int* __restrict__ eli, const float* __restrict__ w2,
    const float* __restrict__ b2, const float* __restrict__ y,
    float* __restrict__ lossOut, float* __restrict__ pred, int M) {
  __shared__ float lsum[4];
  int tid = threadIdx.x;
  int q = tid & 15;
  int lane = tid & 63;
  float w2v[8];
  #pragma unroll
  for (int j = 0; j < 8; ++j) w2v[j] = w2[q * 8 + j];
  float bias = b2[0];
  float lacc = 0.f;
  int e0 = blockIdx.x * 128 + (tid >> 4);
  #pragma unroll
  for (int p = 0; p < 8; ++p) {
    int e = e0 + p * 16;
    if (e < M) {
      int vi = eli[e], di = eli[M + e];
      size_t uo = (size_t)vi * 128 + q * 8;
      size_t vo = (size_t)di * 128 + q * 8;
      f16x8 uh = *(const f16x8*)(UH + uo);
      f16x8 ul = *(const f16x8*)(UL + uo);
      f16x8 vh = *(const f16x8*)(VH + vo);
      f16x8 vl = *(const f16x8*)(VL + vo);
      float part = 0.f;
      #pragma unroll
      for (int j = 0; j < 8; ++j) {
        float t = ((float)uh[j] + (float)ul[j]) + ((float)vh[j] + (float)vl[j]);
        part += fmaxf(t, 0.f) * w2v[j];
      }
      part += __shfl_xor(part, 1);
      part += __shfl_xor(part, 2);
      part += __shfl_xor(part, 4);
      part += __shfl_xor(part, 8);
      if (q == 0) {
        float z = part + bias;
        pred[e] = z;
        lacc += fmaxf(z, 0.f) + log1pf(expf(-fabsf(z))) - z * y[e];
      }
    }
  }
  lacc += __shfl_xor(lacc, 16);
  lacc += __shfl_xor(lacc, 32);
  if (lane == 0) lsum[tid >> 6] = lacc;
  __syncthreads();
  if (tid == 0)
    atomicAdd(lossOut, (lsum[0] + lsum[1] + lsum[2] + lsum[3]) * (1.0f / 200000.0f));
}

// ---------------------------------------------------------------------------
extern "C" void kernel_launch(void* const* d_in, const int* in_sizes, int n_in,
                              void* d_out, int out_size, void* d_ws, size_t ws_size,
                              hipStream_t stream) {
  static const int kRows[6] = {20000, 100000, 4000, 8000, 10000, 4000};
  static const int kOff[6]  = {0, 20000, 120000, 124000, 132000, 142000};
  static const int kSmallT[5]   = {0, 2, 3, 4, 5};
  static const int kInRel[5]    = {1, 2, 4, 6, 8};
  static const int kCbcIn[5]    = {100000, 120000, 224000, 332000, 442000};
  static const int kYOff[5]     = {0, 20000, 24000, 32000, 42000};
  static const int kBOff[5]     = {0, 157, 189, 252, 331};
  static const int kAggOff[5]   = {0, 1250, 1500, 2000, 2625};   // 16-row blocks
  static const int kLeanOff[5]  = {0, 625, 750, 1000, 1313};     // 32-row blocks
  const int kAggTotal = 2875, kLeanTotal = 1438;
  // conv filler split across K2/K3/K4 (K3 small: p2b LDS caps residency)
  const int kConvK2 = 3000, kConvK3 = 1500, kConvK4 = CONV_BLKS - 4500;
  // bucket config (rel order: pv,vp,vs,sv,vpr,prv,vd,dv,vdr,drv)
  static const int kCbcA[NREL]  = {0, 100000, 120000, 124000, 224000,
                                   232000, 332000, 342000, 442000, 446000};
  static const int kEhA[NREL]   = {100000, 100000, 300000, 300000, 200000,
                                   200000, 250000, 250000, 300000, 300000};
  static const int kNdst[NREL]  = {100000, 20000, 4000, 100000, 8000,
                                   100000, 10000, 100000, 4000, 100000};
  static const int kSh[NREL]    = {11, 9, 5, 10, 7, 10, 7, 10, 5, 10};
  static const int kNB[NREL]    = {49, 40, 125, 98, 63, 98, 79, 98, 125, 98};
  static const int kBB[NREL]    = {0, 49, 89, 214, 312, 375, 473, 552, 650, 775};

  const float* W_l = (const float*)d_in[22];
  const float* b_l = (const float*)d_in[23];
  const float* W_r = (const float*)d_in[24];
  const float* cw1 = (const float*)d_in[25];
  const float* cb1 = (const float*)d_in[26];
  const float* cw2 = (const float*)d_in[27];
  const float* cb2 = (const float*)d_in[28];
  const int* eli = (const int*)d_in[29];
  const float* ylab = (const float*)d_in[30];

  // workspace layout
  _Float16* H = (_Float16*)d_ws;                 // XELEMS
  _Float16* L = H + XELEMS;                      // XELEMS
  _Float16* meanH = L + XELEMS;                  // SELEMS
  _Float16* meanL = meanH + SELEMS;              // SELEMS
  _Float16* YH = meanL + SELEMS;                 // SELEMS
  _Float16* Wt = YH + SELEMS;                    // WT_ELEMS
  int* prefix = (int*)(Wt + WT_ELEMS);           // 546,004
  int* counts = prefix + 546004;                 // 546,000 (reused as mprefix)
  int* esrc = counts + NCOUNTS;                  // 2,300,000
  int* partials = esrc + NEDGES;                 // 1,024
  float* visitSumB = (float*)(partials + 1024);  // 512
  int* bcur = (int*)(visitSumB + 512);           // NBKT (+pad)
  int* bdata = bcur + 1024;                      // NBKT * BCAP ints (reused as mesrc)

  int* mprefix = counts;        // free after scan3
  int2* mesrc = (int2*)bdata;   // free after k3 (p2b)

  // classifier U/V tables (alive only after layer-3; reuse dead regions)
  _Float16* UH = meanH;
  _Float16* VH = meanH + (size_t)NVISIT * 128;
  _Float16* VL = VH + (size_t)4000 * 128;
  _Float16* UL = (_Float16*)prefix;

  BkMeta bm;
  for (int r = 0; r < NREL; ++r) {
    bm.ei[r] = (const int*)d_in[12 + r];
    bm.E[r] = kEhA[r];
    bm.cbc[r] = kCbcA[r];
    bm.ndst[r] = kNdst[r];
    bm.sh[r] = kSh[r];
    bm.bb[r] = kBB[r];
    bm.nb[r] = kNB[r];
  }

  PreMeta pm;
  for (int t = 0; t < 6; ++t) {
    pm.nid[t] = (const int*)d_in[2 * t];
    pm.emb[t] = (const float*)d_in[2 * t + 1];
    pm.off[t] = kOff[t];
  }
  pm.W_l = W_l; pm.b_l = b_l; pm.W_r = W_r; pm.cw1 = cw1;
  pm.Wt = Wt; pm.visitSumB = visitSumB;

  hipMemsetAsync(bcur, 0, NBKT * sizeof(int), stream);
  hipMemsetAsync(d_out, 0, sizeof(float), stream);

  // K1: p1 (gating) + prep filler
  k1_p1_prep<<<dim3(740 + 4226), 256, 0, stream>>>(bm, pm, bcur, bdata);
  // K2: p2a (gating) + conv chunk
  k2_p2a_conv<<<dim3(NBKT + kConvK2), 256, 0, stream>>>(bm, pm, bcur, bdata,
                                                        counts, H, L, 0);
  scan1<<<534, 1024, 0, stream>>>(counts, partials);
  scan2<<<1, 1024, 0, stream>>>(partials, 534);
  scan3<<<534, 1024, 0, stream>>>(counts, prefix, partials);
  // K3: p2b (gating) + conv chunk (small: 53KB LDS caps residency)
  k3_p2b_conv<<<dim3(NBKT + kConvK3), 256, 0, stream>>>(bm, pm, bcur, bdata,
                                                        prefix, esrc, H, L, kConvK2);
  // K4: merge (gating) + conv remainder
  k4_merge_conv<<<dim3(NMERGE + kConvK4), 256, 0, stream>>>(pm, prefix, esrc,
                                                            mprefix, mesrc, H, L,
                                                            kConvK2 + kConvK3);

  _Float16* xvH = H + (size_t)kOff[1] * 128;
  _Float16* xvL = L + (size_t)kOff[1] * 128;

  for (int l = 0; l < 4; ++l) {
    int doRelu = (l < 3);
    int last = (l == 3);
    _Float16* LW = Wt + (size_t)l * PLW;

    // F1: agg_small (first) || lean Y_q
    F1Meta f1;
    if (!last) {
      for (int t = 0; t < 5; ++t) {
        f1.rp[t] = prefix + kCbcIn[t];
        f1.mH[t] = meanH + (size_t)kYOff[t] * 128;
        f1.mL[t] = meanL + (size_t)kYOff[t] * 128;
        f1.aM[t] = kRows[kSmallT[t]];
        f1.aOff[t] = kAggOff[t];
      }
      f1.nAgg = 5;
      f1.aggTotal = kAggTotal;
    } else {
      f1.rp[0] = prefix + kCbcIn[4];
      f1.mH[0] = meanH + (size_t)kYOff[4] * 128;
      f1.mL[0] = meanL + (size_t)kYOff[4] * 128;
      f1.aM[0] = 4000;
      f1.aOff[0] = 0;
      for (int t = 1; t < 5; ++t) { f1.rp[t] = nullptr; f1.mH[t] = nullptr; f1.mL[t] = nullptr; f1.aM[t] = 0; f1.aOff[t] = 0; }
      f1.nAgg = 1;
      f1.aggTotal = 250;
    }
    for (int q = 0; q < 5; ++q) {
      size_t so = (size_t)kOff[kSmallT[q]] * 128;
      f1.gAH[q] = H + so;
      f1.gAL[q] = L + so;
      f1.gW[q] = LW + 337920 + (size_t)q * 34816;
      f1.gY[q] = YH + (size_t)kYOff[q] * 128;
      f1.gM[q] = kRows[kSmallT[q]];
      f1.gOff[q] = kLeanOff[q];
    }
    f1.nG = 5;
    fused1<<<dim3(f1.aggTotal + kLeanTotal), 256, 0, stream>>>(f1, xvH, esrc);

    // F2: m1 (small-dst [mean|x_old]@[Wl;Wr]) || m2_visit (in-place), one grid
    MMeta m;
    if (!last) {
      m.nTasks = 6;
      for (int t = 0; t < 5; ++t) {
        size_t mo = (size_t)kYOff[t] * 128;
        size_t so = (size_t)kOff[kSmallT[t]] * 128;
        m.t[t].AH0 = meanH + mo; m.t[t].AL0 = meanL + mo;
        m.t[t].AH1 = H + so;     m.t[t].AL1 = L + so;
        m.t[t].W = LW + (size_t)t * 67584;
        m.t[t].bias = b_l + (size_t)(l * 10 + kInRel[t]) * 128;
        m.t[t].outH = H + so;    m.t[t].outL = L + so;
        m.t[t].M = kRows[kSmallT[t]];
        m.t[t].blkOff = kBOff[t];
        m.t[t].K = 256;
        m.t[t].relu = doRelu;
      }
      m.t[5].AH0 = xvH; m.t[5].AL0 = xvL;
      m.t[5].AH1 = nullptr; m.t[5].AL1 = nullptr;
      m.t[5].W = LW + 512000;
      m.t[5].bias = visitSumB + l * 128;
      m.t[5].outH = xvH; m.t[5].outL = xvL;   // in-place (block-local rows)
      m.t[5].M = NVISIT;
      m.t[5].blkOff = 363;
      m.t[5].K = 128;
      m.t[5].relu = 0;
      mgemm<<<dim3(363 + 782), 256, 0, stream>>>(m);
    } else {
      size_t mo = (size_t)kYOff[4] * 128;
      size_t so = (size_t)kOff[5] * 128;   // drug
      m.nTasks = 2;
      m.t[0].AH0 = meanH + mo; m.t[0].AL0 = meanL + mo;
      m.t[0].AH1 = H + so;     m.t[0].AL1 = L + so;
      m.t[0].W = LW + (size_t)4 * 67584;
      m.t[0].bias = b_l + (size_t)(l * 10 + kInRel[4]) * 128;
      m.t[0].outH = H + so;    m.t[0].outL = L + so;
      m.t[0].M = 4000;
      m.t[0].blkOff = 0;
      m.t[0].K = 256;
      m.t[0].relu = 0;
      m.t[1].AH0 = xvH; m.t[1].AL0 = xvL;
      m.t[1].AH1 = nullptr; m.t[1].AL1 = nullptr;
      m.t[1].W = LW + 512000;
      m.t[1].bias = visitSumB + l * 128;
      m.t[1].outH = xvH; m.t[1].outL = xvL;
      m.t[1].M = NVISIT;
      m.t[1].blkOff = 32;
      m.t[1].K = 128;
      m.t[1].relu = 0;
      mgemm<<<dim3(32 + 782), 256, 0, stream>>>(m);
    }

    // F3: x_v(H,L) += weighted merged gather of YH; relu; re-split
    agg_visit<<<dim3(6250), 256, 0, stream>>>(mprefix, mesrc, YH, xvH, xvL, doRelu);
  }

  // classifier precompute: U = xv@W1top + b1 (split), V = xd@W1bot (split)
  MMeta muv;
  muv.nTasks = 2;
  muv.t[0].AH0 = xvH; muv.t[0].AL0 = xvL;
  muv.t[0].AH1 = nullptr; muv.t[0].AL1 = nullptr;
  muv.t[0].W = Wt + (size_t)4 * PLW;
  muv.t[0].bias = cb1;
  muv.t[0].outH = UH; muv.t[0].outL = UL;
  muv.t[0].M = NVISIT;
  muv.t[0].blkOff = 0;
  muv.t[0].K = 128;
  muv.t[0].relu = 0;
  muv.t[1].AH0 = H + (size_t)kOff[5] * 128; muv.t[1].AL0 = L + (size_t)kOff[5] * 128;
  muv.t[1].AH1 = nullptr; muv.t[1].AL1 = nullptr;
  muv.t[1].W = Wt + (size_t)4 * PLW + 34816;
  muv.t[1].bias = nullptr;
  muv.t[1].outH = VH; muv.t[1].outL = VL;
  muv.t[1].M = 4000;
  muv.t[1].blkOff = 782;
  muv.t[1].K = 128;
  muv.t[1].relu = 0;
  mgemm<<<dim3(782 + 32), 256, 0, stream>>>(muv);

  const int ML = 200000;
  cls_edge<<<dim3((ML + 127) / 128), 256, 0, stream>>>(
      UH, UL, VH, VL, eli, cw2, cb2, ylab,
      (float*)d_out, (float*)d_out + 1, ML);
}